// Round 1
// baseline (283.818 us; speedup 1.0000x reference)
//
#include <hip/hip_runtime.h>
#include <hip/hip_bf16.h>

typedef unsigned short ushort_t;
typedef unsigned int uint_t;

#define DIM   256
#define LSEQ  32768
#define HEADS 8
#define CPG   8
#define EPS   1e-5f

typedef float f32x4 __attribute__((ext_vector_type(4)));
typedef short sfrag8 __attribute__((ext_vector_type(8)));

static __device__ __forceinline__ float b2f(ushort_t u) {
    return __uint_as_float((uint_t)u << 16);
}
static __device__ __forceinline__ ushort_t f2bs(float f) {
    union { __hip_bfloat16 h; ushort_t u; } cv;
    cv.h = __float2bfloat16(f);
    return cv.u;
}
static __device__ __forceinline__ uint_t pk2(float a, float b) {
    return (uint_t)f2bs(a) | ((uint_t)f2bs(b) << 16);
}
static __device__ __forceinline__ void glds16(const ushort_t* g, ushort_t* l) {
    __builtin_amdgcn_global_load_lds((const __attribute__((address_space(1))) uint_t*)g,
                                     (__attribute__((address_space(3))) uint_t*)l, 16, 0, 0);
}

// ============ fused transpose + group stats: pure-register 4x4 micro-transpose ============
__global__ __launch_bounds__(256) void k_tr(const float* __restrict__ x,
                                            ushort_t* __restrict__ XT,
                                            float* __restrict__ gsum,
                                            float* __restrict__ gsumsq) {
    const int tid   = threadIdx.x;
    const int lane  = tid & 63;
    const int wv    = tid >> 6;
    const int l_blk = lane >> 3;
    const int c_blk = lane & 7;
    const int c0    = (blockIdx.x & 1) * 128;
    const int l0b   = (blockIdx.x >> 1) * 128;
    const int cb    = c0 + 32 * wv + 4 * c_blk;

    const float* xr0 = x + (size_t)(cb + 0) * LSEQ;
    const float* xr1 = x + (size_t)(cb + 1) * LSEQ;
    const float* xr2 = x + (size_t)(cb + 2) * LSEQ;
    const float* xr3 = x + (size_t)(cb + 3) * LSEQ;

    float s = 0.f, s2 = 0.f;

    #pragma unroll
    for (int t = 0; t < 4; t++) {
        const int l = l0b + 32 * t + 4 * l_blk;
        float4 a = *(const float4*)(xr0 + l);
        float4 b = *(const float4*)(xr1 + l);
        float4 c = *(const float4*)(xr2 + l);
        float4 d = *(const float4*)(xr3 + l);

        s  += (a.x + a.y + a.z + a.w) + (b.x + b.y + b.z + b.w)
            + (c.x + c.y + c.z + c.w) + (d.x + d.y + d.z + d.w);
        s2 += (a.x*a.x + a.y*a.y + a.z*a.z + a.w*a.w)
            + (b.x*b.x + b.y*b.y + b.z*b.z + b.w*b.w)
            + (c.x*c.x + c.y*c.y + c.z*c.z + c.w*c.w)
            + (d.x*d.x + d.y*d.y + d.z*d.z + d.w*d.w);

        ushort_t* dst = XT + (size_t)l * 256 + cb;
        uint2 p0; p0.x = pk2(a.x, b.x); p0.y = pk2(c.x, d.x);
        uint2 p1; p1.x = pk2(a.y, b.y); p1.y = pk2(c.y, d.y);
        uint2 p2; p2.x = pk2(a.z, b.z); p2.y = pk2(c.z, d.z);
        uint2 p3; p3.x = pk2(a.w, b.w); p3.y = pk2(c.w, d.w);
        *(uint2*)(dst)           = p0;
        *(uint2*)(dst + 256)     = p1;
        *(uint2*)(dst + 512)     = p2;
        *(uint2*)(dst + 768)     = p3;
    }

    s  += __shfl_xor(s, 1);   s2 += __shfl_xor(s2, 1);
    s  += __shfl_xor(s, 8);   s2 += __shfl_xor(s2, 8);
    s  += __shfl_xor(s, 16);  s2 += __shfl_xor(s2, 16);
    s  += __shfl_xor(s, 32);  s2 += __shfl_xor(s2, 32);
    if (l_blk == 0 && (c_blk & 1) == 0) {
        int g = ((c0 + 32 * wv) >> 3) + (c_blk >> 1);
        atomicAdd(&gsum[g], s);
        atomicAdd(&gsumsq[g], s2);
    }
}

// ============ a[c], bb[c] ============
__global__ void k_ab(const float* __restrict__ gn_w, const float* __restrict__ gn_b,
                     const float* __restrict__ gsum, const float* __restrict__ gsumsq,
                     float* __restrict__ A, float* __restrict__ BB) {
    int c = threadIdx.x;
    int g = c >> 3;
    const float inv_n = 1.f / (float)(CPG * LSEQ);
    float mu  = gsum[g] * inv_n;
    float var = gsumsq[g] * inv_n - mu * mu;
    float inv = rsqrtf(var + EPS);
    float a = gn_w[c] * inv;
    A[c]  = a;
    BB[c] = gn_b[c] - mu * a;
}

// ============ folded qkv biases ============
__global__ void k_fold_b(const float* __restrict__ w_qkv, const float* __restrict__ b_qkv,
                         const float* __restrict__ BB, float* __restrict__ BE) {
    int r = blockIdx.x * 256 + threadIdx.x;   // 1536
    float s = b_qkv[r];
    const float4* wr = (const float4*)(w_qkv + (size_t)r * DIM);
    const float4* bb = (const float4*)BB;
    #pragma unroll 4
    for (int c4 = 0; c4 < 64; c4++) {
        float4 w = wr[c4], b = bb[c4];
        s += w.x*b.x + w.y*b.y + w.z*b.z + w.w*b.w;
    }
    BE[r] = s;
}

// ============ folded k/v weights: WEB bf16 [r'][c], r' = h*128 + part*64 + j ============
__global__ void k_fold_w(const float* __restrict__ w_qkv, const float* __restrict__ A,
                         const float* __restrict__ BE,
                         ushort_t* __restrict__ WEB, float* __restrict__ BE2) {
    int idx = blockIdx.x * 256 + threadIdx.x;   // 262144
    int rp = idx >> 8, c = idx & 255;
    int h = rp >> 7, sub = rp & 127, part = sub >> 6, j = sub & 63;
    int orig = 512 + part * 512 + h * 64 + j;
    WEB[(size_t)rp * 256 + c] = f2bs(w_qkv[(size_t)orig * 256 + c] * A[c]);
    if (c == 0) BE2[rp] = BE[orig];
}

// ============ fused kv-GEMM + exp + context GEMM ============
// grid 2048: h = bid>>8 (8 sharers of a col-block differ by 256 -> same XCD L2),
// col-block = bid&255 -> 128 cols, processed as 4 chunks of 32.
// Staging: global_load_lds width-16, double-buffered xs, source-granule XOR-swizzle
// (g ^ (row&7)) so linear LDS writes + swizzled ds_read_b128 are conflict-free.
// Z accumulated in registers by the ek-producing waves (no scalar LDS re-read loop).
__global__ __launch_bounds__(256, 3) void k_attn(const ushort_t* __restrict__ XT,
                                                 const ushort_t* __restrict__ WEB,
                                                 const float* __restrict__ BE2,
                                                 float* __restrict__ S, float* __restrict__ Z) {
    __shared__ __align__(16) ushort_t xs[2][32 * 256];
    __shared__ __align__(16) ushort_t ek[64 * 40];
    __shared__ __align__(16) ushort_t vv[64 * 40];
    const int tid  = threadIdx.x;
    const int lane = tid & 63;
    const int wv   = __builtin_amdgcn_readfirstlane(tid >> 6);
    const int ln   = lane & 15;
    const int q    = lane >> 4;
    const int h    = blockIdx.x >> 8;
    const int cg0  = (blockIdx.x & 255) * 128;

    const int srow = lane >> 5;      // 0/1: which of the 2 rows this glds call covers
    const int sg   = lane & 31;      // 16B granule within a 512B row
    const int swz  = ln & 7;

    // A fragments: WEB rows h*128 + wv*32 + mt*16 + ln (waves 0,1 = K rows, 2,3 = V rows)
    sfrag8 Af[2][8];
    #pragma unroll
    for (int mt = 0; mt < 2; mt++) {
        const ushort_t* ap = WEB + (size_t)(h*128 + wv*32 + mt*16 + ln) * 256 + q*8;
        #pragma unroll
        for (int k0 = 0; k0 < 8; k0++) Af[mt][k0] = *(const sfrag8*)(ap + k0*32);
    }
    float bias[2][4];
    #pragma unroll
    for (int mt = 0; mt < 2; mt++)
        #pragma unroll
        for (int r = 0; r < 4; r++)
            bias[mt][r] = BE2[h*128 + wv*32 + mt*16 + q*4 + r];

    f32x4 Sacc[4];
    #pragma unroll
    for (int nt = 0; nt < 4; nt++)
        #pragma unroll
        for (int e = 0; e < 4; e++) Sacc[nt][e] = 0.f;
    float zp[8];
    #pragma unroll
    for (int i = 0; i < 8; i++) zp[i] = 0.f;

    // prologue: stage chunk 0 into buffer 0
    #pragma unroll
    for (int kk = 0; kk < 4; kk++) {
        const int row = wv*8 + kk*2 + srow;
        glds16(XT + (size_t)(cg0 + row) * 256 + ((sg ^ (row & 7)) << 3),
               &xs[0][(wv*8 + kk*2) * 256]);
    }

    for (int t = 0; t < 4; t++) {
        __syncthreads();   // drains vmcnt -> buf[t&1] ready; also fences prev GEMM2 ek/vv reads

        if (t < 3) {       // issue async stage of chunk t+1 into the other buffer
            const int l0n = cg0 + (t + 1) * 32;
            #pragma unroll
            for (int kk = 0; kk < 4; kk++) {
                const int row = wv*8 + kk*2 + srow;
                glds16(XT + (size_t)(l0n + row) * 256 + ((sg ^ (row & 7)) << 3),
                       &xs[(t + 1) & 1][(wv*8 + kk*2) * 256]);
            }
        }

        const ushort_t* xb = xs[t & 1];
        f32x4 acc[2][2];
        #pragma unroll
        for (int mt = 0; mt < 2; mt++)
            #pragma unroll
            for (int nt = 0; nt < 2; nt++)
                #pragma unroll
                for (int e = 0; e < 4; e++) acc[mt][nt][e] = 0.f;

        // GEMM1: 32 rows (2 m-tiles) x 32 cols (2 n-tiles), K=256, swizzled B-reads
        #pragma unroll
        for (int k0 = 0; k0 < 8; k0++) {
            const int gg = ((4*k0 + q) ^ swz) << 3;
            sfrag8 b0 = *(const sfrag8*)&xb[(0*16 + ln) * 256 + gg];
            sfrag8 b1 = *(const sfrag8*)&xb[(1*16 + ln) * 256 + gg];
            #pragma unroll
            for (int mt = 0; mt < 2; mt++) {
                acc[mt][0] = __builtin_amdgcn_mfma_f32_16x16x32_bf16(Af[mt][k0], b0, acc[mt][0], 0, 0, 0);
                acc[mt][1] = __builtin_amdgcn_mfma_f32_16x16x32_bf16(Af[mt][k0], b1, acc[mt][1], 0, 0, 0);
            }
        }

        // waves 0,1 -> ek (with exp, z-partials in registers); waves 2,3 -> vv
        if (wv < 2) {
            #pragma unroll
            for (int mt = 0; mt < 2; mt++)
                #pragma unroll
                for (int nt = 0; nt < 2; nt++)
                    #pragma unroll
                    for (int r = 0; r < 4; r++) {
                        int row = wv*32 + mt*16 + q*4 + r;
                        int col = nt*16 + ln;
                        float e = __expf(acc[mt][nt][r] + bias[mt][r]);
                        ek[row * 40 + col] = f2bs(e);
                        zp[mt*4 + r] += e;
                    }
        } else {
            #pragma unroll
            for (int mt = 0; mt < 2; mt++)
                #pragma unroll
                for (int nt = 0; nt < 2; nt++)
                    #pragma unroll
                    for (int r = 0; r < 4; r++) {
                        int row = (wv - 2)*32 + mt*16 + q*4 + r;
                        int col = nt*16 + ln;
                        vv[row * 40 + col] = f2bs(acc[mt][nt][r] + bias[mt][r]);
                    }
        }
        __syncthreads();

        // GEMM2: S += ek @ vv^T (K=32, single k-step)
        {
            sfrag8 a = *(const sfrag8*)&ek[(wv*16 + ln) * 40 + q*8];
            #pragma unroll
            for (int nt = 0; nt < 4; nt++) {
                sfrag8 b = *(const sfrag8*)&vv[(nt*16 + ln) * 40 + q*8];
                Sacc[nt] = __builtin_amdgcn_mfma_f32_16x16x32_bf16(a, b, Sacc[nt], 0, 0, 0);
            }
        }
    }

    float* Sh = S + h * 4096;
    #pragma unroll
    for (int nt = 0; nt < 4; nt++)
        #pragma unroll
        for (int r = 0; r < 4; r++)
            atomicAdd(&Sh[(wv*16 + q*4 + r) * 64 + nt*16 + ln], Sacc[nt][r]);

    if (wv < 2) {
        #pragma unroll
        for (int i = 0; i < 8; i++) {
            float z = zp[i];
            z += __shfl_xor(z, 1);
            z += __shfl_xor(z, 2);
            z += __shfl_xor(z, 4);
            z += __shfl_xor(z, 8);
            if (ln == 0) {
                int row = wv*32 + (i >> 2)*16 + q*4 + (i & 3);
                atomicAdd(&Z[h*64 + row], z);
            }
        }
    }
}

// ============ W2[d][hc] = sum_e w_out[d][h64+e] * S[hc][e] / Z[hc] ============
__global__ void k_w2(const float* __restrict__ w_out, const float* __restrict__ S,
                     const float* __restrict__ Z, float* __restrict__ W2) {
    int d  = blockIdx.x >> 1;
    int hc = ((blockIdx.x & 1) << 8) + threadIdx.x;
    int h64 = hc & ~63;
    float invZ = 1.f / Z[hc];
    const float4* wo = (const float4*)(w_out + (size_t)d * 512 + h64);
    const float4* Sr = (const float4*)(S + (size_t)hc * 64);
    float s = 0.f;
    #pragma unroll
    for (int e4 = 0; e4 < 16; e4++) {
        float4 a = wo[e4], b = Sr[e4];
        s += a.x*b.x + a.y*b.y + a.z*b.z + a.w*b.w;
    }
    W2[(size_t)d * 512 + hc] = s * invZ;
}

// ============ W3B[d][c] bf16 + B3[d] ============
__global__ void k_w3(const float* __restrict__ w_qkv, const float* __restrict__ W2,
                     const float* __restrict__ A, const float* __restrict__ BE,
                     const float* __restrict__ b_out,
                     ushort_t* __restrict__ W3B, float* __restrict__ B3) {
    int d = blockIdx.x, c = threadIdx.x;
    const float* W2d = W2 + (size_t)d * 512;
    float s = 0.f;
    #pragma unroll 4
    for (int hc = 0; hc < 512; hc++)
        s += W2d[hc] * w_qkv[(size_t)hc * 256 + c];
    W3B[(size_t)d * 256 + c] = f2bs(s * A[c]);
    __shared__ float red[256];
    red[c] = W2d[c] * BE[c] + W2d[256 + c] * BE[256 + c];
    __syncthreads();
    for (int off = 128; off > 0; off >>= 1) {
        if (c < off) red[c] += red[c + off];
        __syncthreads();
    }
    if (c == 0) B3[d] = b_out[d] + red[0];
}

// ============ final GEMM: out = W3B @ xT + b3 ============
// grid 1024: m0 = (bid>>9)*128, chunk = bid&511 (XCD pairing). Wave owns 32 rows x 64 cols.
__global__ __launch_bounds__(256, 2) void k_final(const ushort_t* __restrict__ XT,
                                                  const ushort_t* __restrict__ W3B,
                                                  const float* __restrict__ B3,
                                                  float* __restrict__ out) {
    __shared__ __align__(16) ushort_t xs[64 * 264];
    const int tid  = threadIdx.x;
    const int lane = tid & 63;
    const int wv   = __builtin_amdgcn_readfirstlane(tid >> 6);
    const int ln   = lane & 15;
    const int q    = lane >> 4;
    const int m0   = (blockIdx.x >> 9) * 128;
    const int l0   = (blockIdx.x & 511) * 64;

    sfrag8 Af[2][8];
    #pragma unroll
    for (int mt = 0; mt < 2; mt++) {
        const ushort_t* ap = W3B + (size_t)(m0 + wv*32 + mt*16 + ln) * 256 + q*8;
        #pragma unroll
        for (int k0 = 0; k0 < 8; k0++) Af[mt][k0] = *(const sfrag8*)(ap + k0*32);
    }
    float bias[2][4];
    #pragma unroll
    for (int mt = 0; mt < 2; mt++)
        #pragma unroll
        for (int r = 0; r < 4; r++)
            bias[mt][r] = B3[m0 + wv*32 + mt*16 + q*4 + r];

    #pragma unroll
    for (int it = 0; it < 8; it++) {
        int idx = it * 256 + tid;
        int row = idx >> 5, seg = idx & 31;
        *(uint4*)&xs[row * 264 + seg * 8] =
            *(const uint4*)(XT + (size_t)(l0 + row) * 256 + seg * 8);
    }
    __syncthreads();

    f32x4 acc[2][4];
    #pragma unroll
    for (int mt = 0; mt < 2; mt++)
        #pragma unroll
        for (int nt = 0; nt < 4; nt++)
            #pragma unroll
            for (int e = 0; e < 4; e++) acc[mt][nt][e] = 0.f;

    #pragma unroll
    for (int k0 = 0; k0 < 8; k0++) {
        sfrag8 b0 = *(const sfrag8*)&xs[(0*16 + ln) * 264 + k0*32 + q*8];
        sfrag8 b1 = *(const sfrag8*)&xs[(1*16 + ln) * 264 + k0*32 + q*8];
        sfrag8 b2 = *(const sfrag8*)&xs[(2*16 + ln) * 264 + k0*32 + q*8];
        sfrag8 b3 = *(const sfrag8*)&xs[(3*16 + ln) * 264 + k0*32 + q*8];
        #pragma unroll
        for (int mt = 0; mt < 2; mt++) {
            acc[mt][0] = __builtin_amdgcn_mfma_f32_16x16x32_bf16(Af[mt][k0], b0, acc[mt][0], 0, 0, 0);
            acc[mt][1] = __builtin_amdgcn_mfma_f32_16x16x32_bf16(Af[mt][k0], b1, acc[mt][1], 0, 0, 0);
            acc[mt][2] = __builtin_amdgcn_mfma_f32_16x16x32_bf16(Af[mt][k0], b2, acc[mt][2], 0, 0, 0);
            acc[mt][3] = __builtin_amdgcn_mfma_f32_16x16x32_bf16(Af[mt][k0], b3, acc[mt][3], 0, 0, 0);
        }
    }

    #pragma unroll
    for (int mt = 0; mt < 2; mt++)
        #pragma unroll
        for (int nt = 0; nt < 4; nt++)
            #pragma unroll
            for (int r = 0; r < 4; r++) {
                int row = m0 + wv*32 + mt*16 + q*4 + r;
                int col = l0 + nt*16 + ln;
                out[(size_t)row * LSEQ + col] = acc[mt][nt][r] + bias[mt][r];
            }
}

// ============ launch ============
extern "C" void kernel_launch(void* const* d_in, const int* in_sizes, int n_in,
                              void* d_out, int out_size, void* d_ws, size_t ws_size,
                              hipStream_t stream) {
    const float* x     = (const float*)d_in[0];
    const float* gn_w  = (const float*)d_in[1];
    const float* gn_b  = (const float*)d_in[2];
    const float* w_qkv = (const float*)d_in[3];
    const float* b_qkv = (const float*)d_in[4];
    const float* w_out = (const float*)d_in[5];
    const float* b_out = (const float*)d_in[6];
    float* out = (float*)d_out;
    float* ws  = (float*)d_ws;

    float*    gsum   = ws + 0;        // 32
    float*    gsumsq = ws + 32;       // 32
    float*    S      = ws + 64;       // 32768
    float*    Z      = ws + 32832;    // 512   [zeroed through 33344]
    float*    A      = ws + 33344;    // 256
    float*    BB     = ws + 33600;    // 256
    float*    BE     = ws + 33856;    // 1536
    float*    BE2    = ws + 35392;    // 1024
    ushort_t* WEB    = (ushort_t*)(ws + 36416);    // 1024*256 bf16 (65536 f)
    float*    W2     = ws + 101952;   // 131072
    ushort_t* W3B    = (ushort_t*)(ws + 233024);   // 256*256 bf16 (32768 f)
    float*    B3     = ws + 265792;   // 256
    ushort_t* XT     = (ushort_t*)(ws + 266048);   // 32768*256 bf16 (4194304 f)

    hipMemsetAsync(ws, 0, 33344 * sizeof(float), stream);   // gsum, gsumsq, S, Z
    k_tr    <<<512,  256, 0, stream>>>(x, XT, gsum, gsumsq);
    k_ab    <<<1,    256, 0, stream>>>(gn_w, gn_b, gsum, gsumsq, A, BB);
    k_fold_b<<<6,    256, 0, stream>>>(w_qkv, b_qkv, BB, BE);
    k_fold_w<<<1024, 256, 0, stream>>>(w_qkv, A, BE, WEB, BE2);
    k_attn  <<<2048, 256, 0, stream>>>(XT, WEB, BE2, S, Z);
    k_w2    <<<512,  256, 0, stream>>>(w_out, S, Z, W2);
    k_w3    <<<256,  256, 0, stream>>>(w_qkv, W2, A, BE, b_out, W3B, B3);
    k_final <<<1024, 256, 0, stream>>>(XT, W3B, B3, out);
}

// Round 2
// 247.864 us; speedup vs baseline: 1.1451x; 1.1451x over previous
//
#include <hip/hip_runtime.h>
#include <hip/hip_bf16.h>

typedef unsigned short ushort_t;
typedef unsigned int uint_t;

#define DIM   256
#define LSEQ  32768
#define HEADS 8
#define CPG   8
#define EPS   1e-5f

typedef float f32x4 __attribute__((ext_vector_type(4)));
typedef short sfrag8 __attribute__((ext_vector_type(8)));

static __device__ __forceinline__ float b2f(ushort_t u) {
    return __uint_as_float((uint_t)u << 16);
}
static __device__ __forceinline__ ushort_t f2bs(float f) {
    union { __hip_bfloat16 h; ushort_t u; } cv;
    cv.h = __float2bfloat16(f);
    return cv.u;
}
static __device__ __forceinline__ uint_t pk2(float a, float b) {
    return (uint_t)f2bs(a) | ((uint_t)f2bs(b) << 16);
}
static __device__ __forceinline__ void glds16(const ushort_t* g, ushort_t* l) {
    __builtin_amdgcn_global_load_lds((const __attribute__((address_space(1))) uint_t*)g,
                                     (__attribute__((address_space(3))) uint_t*)l, 16, 0, 0);
}

// ============ fused transpose + group stats: pure-register 4x4 micro-transpose ============
__global__ __launch_bounds__(256) void k_tr(const float* __restrict__ x,
                                            ushort_t* __restrict__ XT,
                                            float* __restrict__ gsum,
                                            float* __restrict__ gsumsq) {
    const int tid   = threadIdx.x;
    const int lane  = tid & 63;
    const int wv    = tid >> 6;
    const int l_blk = lane >> 3;
    const int c_blk = lane & 7;
    const int c0    = (blockIdx.x & 1) * 128;
    const int l0b   = (blockIdx.x >> 1) * 128;
    const int cb    = c0 + 32 * wv + 4 * c_blk;

    const float* xr0 = x + (size_t)(cb + 0) * LSEQ;
    const float* xr1 = x + (size_t)(cb + 1) * LSEQ;
    const float* xr2 = x + (size_t)(cb + 2) * LSEQ;
    const float* xr3 = x + (size_t)(cb + 3) * LSEQ;

    float s = 0.f, s2 = 0.f;

    #pragma unroll
    for (int t = 0; t < 4; t++) {
        const int l = l0b + 32 * t + 4 * l_blk;
        float4 a = *(const float4*)(xr0 + l);
        float4 b = *(const float4*)(xr1 + l);
        float4 c = *(const float4*)(xr2 + l);
        float4 d = *(const float4*)(xr3 + l);

        s  += (a.x + a.y + a.z + a.w) + (b.x + b.y + b.z + b.w)
            + (c.x + c.y + c.z + c.w) + (d.x + d.y + d.z + d.w);
        s2 += (a.x*a.x + a.y*a.y + a.z*a.z + a.w*a.w)
            + (b.x*b.x + b.y*b.y + b.z*b.z + b.w*b.w)
            + (c.x*c.x + c.y*c.y + c.z*c.z + c.w*c.w)
            + (d.x*d.x + d.y*d.y + d.z*d.z + d.w*d.w);

        ushort_t* dst = XT + (size_t)l * 256 + cb;
        uint2 p0; p0.x = pk2(a.x, b.x); p0.y = pk2(c.x, d.x);
        uint2 p1; p1.x = pk2(a.y, b.y); p1.y = pk2(c.y, d.y);
        uint2 p2; p2.x = pk2(a.z, b.z); p2.y = pk2(c.z, d.z);
        uint2 p3; p3.x = pk2(a.w, b.w); p3.y = pk2(c.w, d.w);
        *(uint2*)(dst)           = p0;
        *(uint2*)(dst + 256)     = p1;
        *(uint2*)(dst + 512)     = p2;
        *(uint2*)(dst + 768)     = p3;
    }

    s  += __shfl_xor(s, 1);   s2 += __shfl_xor(s2, 1);
    s  += __shfl_xor(s, 8);   s2 += __shfl_xor(s2, 8);
    s  += __shfl_xor(s, 16);  s2 += __shfl_xor(s2, 16);
    s  += __shfl_xor(s, 32);  s2 += __shfl_xor(s2, 32);
    if (l_blk == 0 && (c_blk & 1) == 0) {
        int g = ((c0 + 32 * wv) >> 3) + (c_blk >> 1);
        atomicAdd(&gsum[g], s);
        atomicAdd(&gsumsq[g], s2);
    }
}

// ============ a[c], bb[c] ============
__global__ void k_ab(const float* __restrict__ gn_w, const float* __restrict__ gn_b,
                     const float* __restrict__ gsum, const float* __restrict__ gsumsq,
                     float* __restrict__ A, float* __restrict__ BB) {
    int c = threadIdx.x;
    int g = c >> 3;
    const float inv_n = 1.f / (float)(CPG * LSEQ);
    float mu  = gsum[g] * inv_n;
    float var = gsumsq[g] * inv_n - mu * mu;
    float inv = rsqrtf(var + EPS);
    float a = gn_w[c] * inv;
    A[c]  = a;
    BB[c] = gn_b[c] - mu * a;
}

// ============ folded qkv biases ============
__global__ void k_fold_b(const float* __restrict__ w_qkv, const float* __restrict__ b_qkv,
                         const float* __restrict__ BB, float* __restrict__ BE) {
    int r = blockIdx.x * 256 + threadIdx.x;   // 1536
    float s = b_qkv[r];
    const float4* wr = (const float4*)(w_qkv + (size_t)r * DIM);
    const float4* bb = (const float4*)BB;
    #pragma unroll 4
    for (int c4 = 0; c4 < 64; c4++) {
        float4 w = wr[c4], b = bb[c4];
        s += w.x*b.x + w.y*b.y + w.z*b.z + w.w*b.w;
    }
    BE[r] = s;
}

// ============ folded k/v weights: WEB bf16 [r'][c], r' = h*128 + part*64 + j ============
__global__ void k_fold_w(const float* __restrict__ w_qkv, const float* __restrict__ A,
                         const float* __restrict__ BE,
                         ushort_t* __restrict__ WEB, float* __restrict__ BE2) {
    int idx = blockIdx.x * 256 + threadIdx.x;   // 262144
    int rp = idx >> 8, c = idx & 255;
    int h = rp >> 7, sub = rp & 127, part = sub >> 6, j = sub & 63;
    int orig = 512 + part * 512 + h * 64 + j;
    WEB[(size_t)rp * 256 + c] = f2bs(w_qkv[(size_t)orig * 256 + c] * A[c]);
    if (c == 0) BE2[rp] = BE[orig];
}

// ============ fused kv-GEMM + exp + context GEMM (v3) ============
// grid 512 x 512 threads (8 waves). h = bid>>6, superchunk = bid&63 (512 cols, 8 chunks of 64).
// Wave layout: mh = wv>>2 (0: K rows 0-63 -> ek, 1: V rows 64-127 -> vv), nh = wv&3 (16 cols).
// -> each wave re-reads only its 16-col slice of xs (re-read factor 2 vs 4): 8 ds_read_b128
//    b-frags feed 32 MFMAs per iter.
// Staging: global_load_lds w16 direct to LDS, double-buffered, source-granule XOR-swizzle
// (granule ^ (row&7)) so linear DMA writes + swizzled ds_read_b128 are bank-balanced.
// Barriers: raw s_barrier; mid barrier drains ONLY lgkmcnt (prefetch vmcnt stays in flight);
// vmcnt(0) deferred to end-of-iter barrier (loads covered by GEMM1+ek/vv+GEMM2 latency).
// Z accumulated in registers by the ek waves.
__global__ __launch_bounds__(512, 2) void k_attn(const ushort_t* __restrict__ XT,
                                                 const ushort_t* __restrict__ WEB,
                                                 const float* __restrict__ BE2,
                                                 float* __restrict__ S, float* __restrict__ Z) {
    __shared__ __align__(16) ushort_t xs[2][64 * 256];
    __shared__ __align__(16) ushort_t ek[64 * 72];
    __shared__ __align__(16) ushort_t vv[64 * 72];
    const int tid  = threadIdx.x;
    const int lane = tid & 63;
    const int wv   = __builtin_amdgcn_readfirstlane(tid >> 6);
    const int ln   = lane & 15;
    const int q    = lane >> 4;
    const int mh   = wv >> 2;          // 0: ek (K rows), 1: vv (V rows)
    const int nh   = wv & 3;           // 16-col slice
    const int h    = blockIdx.x >> 6;
    const int cg0  = (blockIdx.x & 63) * 512;

    const int srow = lane >> 5;        // which of the 2 rows this glds covers
    const int sg   = lane & 31;        // 16B granule within a 512B row
    const int colr = nh * 16 + ln;     // xs row this lane reads in GEMM1
    const int cswz = colr & 7;

    // A fragments: 64 rows x K=256 -> Af[4][8] = 128 VGPRs
    sfrag8 Af[4][8];
    #pragma unroll
    for (int mt = 0; mt < 4; mt++) {
        const ushort_t* ap = WEB + (size_t)(h*128 + mh*64 + mt*16 + ln) * 256 + q*8;
        #pragma unroll
        for (int k0 = 0; k0 < 8; k0++) Af[mt][k0] = *(const sfrag8*)(ap + k0*32);
    }
    float bias[4][4];
    #pragma unroll
    for (int mt = 0; mt < 4; mt++)
        #pragma unroll
        for (int r = 0; r < 4; r++)
            bias[mt][r] = BE2[h*128 + mh*64 + mt*16 + q*4 + r];

    f32x4 Sacc[2];
    #pragma unroll
    for (int nt = 0; nt < 2; nt++)
        #pragma unroll
        for (int e = 0; e < 4; e++) Sacc[nt][e] = 0.f;
    float zp[16];
    #pragma unroll
    for (int i = 0; i < 16; i++) zp[i] = 0.f;

    // prologue: stage chunk 0 into buffer 0 (each wave stages its 8 rows)
    #pragma unroll
    for (int kk = 0; kk < 4; kk++) {
        const int row = wv*8 + kk*2 + srow;
        glds16(XT + (size_t)(cg0 + row) * 256 + ((sg ^ (row & 7)) << 3),
               &xs[0][(wv*8 + kk*2) * 256]);
    }
    asm volatile("s_waitcnt vmcnt(0)" ::: "memory");
    __builtin_amdgcn_s_barrier();

    for (int t = 0; t < 8; t++) {
        const int buf = t & 1;

        if (t < 7) {   // issue-early async stage of chunk t+1 into the other buffer
            const int l0n = cg0 + (t + 1) * 64;
            #pragma unroll
            for (int kk = 0; kk < 4; kk++) {
                const int row = wv*8 + kk*2 + srow;
                glds16(XT + (size_t)(l0n + row) * 256 + ((sg ^ (row & 7)) << 3),
                       &xs[buf ^ 1][(wv*8 + kk*2) * 256]);
            }
        }

        // GEMM1: 64 rows (4 m-tiles) x 16 cols (1 n-tile), K=256
        const ushort_t* xb = xs[buf];
        f32x4 acc[4];
        #pragma unroll
        for (int mt = 0; mt < 4; mt++)
            #pragma unroll
            for (int e = 0; e < 4; e++) acc[mt][e] = 0.f;

        #pragma unroll
        for (int k0 = 0; k0 < 8; k0++) {
            sfrag8 b = *(const sfrag8*)&xb[colr * 256 + (((k0*4 + q) ^ cswz) << 3)];
            #pragma unroll
            for (int mt = 0; mt < 4; mt++)
                acc[mt] = __builtin_amdgcn_mfma_f32_16x16x32_bf16(Af[mt][k0], b, acc[mt], 0, 0, 0);
        }

        // ek (with exp + register z-partials) / vv writes
        if (mh == 0) {
            #pragma unroll
            for (int mt = 0; mt < 4; mt++)
                #pragma unroll
                for (int r = 0; r < 4; r++) {
                    int row = mt*16 + q*4 + r;
                    float e = __expf(acc[mt][r] + bias[mt][r]);
                    ek[row * 72 + colr] = f2bs(e);
                    zp[mt*4 + r] += e;
                }
        } else {
            #pragma unroll
            for (int mt = 0; mt < 4; mt++)
                #pragma unroll
                for (int r = 0; r < 4; r++) {
                    int row = mt*16 + q*4 + r;
                    vv[row * 72 + colr] = f2bs(acc[mt][r] + bias[mt][r]);
                }
        }
        // mid barrier: drain LDS ops only; staged global loads stay in flight
        asm volatile("s_waitcnt lgkmcnt(0)" ::: "memory");
        __builtin_amdgcn_s_barrier();

        // GEMM2: S += ek @ vv^T (K=64). Wave owns S rows (wv&3)*16, cols (wv>>2)*32.
        {
            const int sr = wv & 3, sc = wv >> 2;
            #pragma unroll
            for (int k0 = 0; k0 < 2; k0++) {
                sfrag8 a = *(const sfrag8*)&ek[(sr*16 + ln) * 72 + k0*32 + q*8];
                #pragma unroll
                for (int nt = 0; nt < 2; nt++) {
                    sfrag8 b = *(const sfrag8*)&vv[(sc*32 + nt*16 + ln) * 72 + k0*32 + q*8];
                    Sacc[nt] = __builtin_amdgcn_mfma_f32_16x16x32_bf16(a, b, Sacc[nt], 0, 0, 0);
                }
            }
        }
        // end barrier: staged loads complete + all GEMM2 LDS reads complete
        asm volatile("s_waitcnt vmcnt(0) lgkmcnt(0)" ::: "memory");
        __builtin_amdgcn_s_barrier();
    }

    float* Sh = S + h * 4096;
    {
        const int sr = wv & 3, sc = wv >> 2;
        #pragma unroll
        for (int nt = 0; nt < 2; nt++)
            #pragma unroll
            for (int r = 0; r < 4; r++)
                atomicAdd(&Sh[(sr*16 + q*4 + r) * 64 + sc*32 + nt*16 + ln], Sacc[nt][r]);
    }

    if (mh == 0) {
        #pragma unroll
        for (int i = 0; i < 16; i++) {
            float z = zp[i];
            z += __shfl_xor(z, 1);
            z += __shfl_xor(z, 2);
            z += __shfl_xor(z, 4);
            z += __shfl_xor(z, 8);
            if (ln == 0) {
                int row = (i >> 2)*16 + q*4 + (i & 3);
                atomicAdd(&Z[h*64 + row], z);
            }
        }
    }
}

// ============ W2[d][hc] = sum_e w_out[d][h64+e] * S[hc][e] / Z[hc] ============
__global__ void k_w2(const float* __restrict__ w_out, const float* __restrict__ S,
                     const float* __restrict__ Z, float* __restrict__ W2) {
    int d  = blockIdx.x >> 1;
    int hc = ((blockIdx.x & 1) << 8) + threadIdx.x;
    int h64 = hc & ~63;
    float invZ = 1.f / Z[hc];
    const float4* wo = (const float4*)(w_out + (size_t)d * 512 + h64);
    const float4* Sr = (const float4*)(S + (size_t)hc * 64);
    float s = 0.f;
    #pragma unroll
    for (int e4 = 0; e4 < 16; e4++) {
        float4 a = wo[e4], b = Sr[e4];
        s += a.x*b.x + a.y*b.y + a.z*b.z + a.w*b.w;
    }
    W2[(size_t)d * 512 + hc] = s * invZ;
}

// ============ W3B[d][c] bf16 + B3[d]: 512 threads, hc split across 2 halves ============
__global__ void k_w3(const float* __restrict__ w_qkv, const float* __restrict__ W2,
                     const float* __restrict__ A, const float* __restrict__ BE,
                     const float* __restrict__ b_out,
                     ushort_t* __restrict__ W3B, float* __restrict__ B3) {
    int d = blockIdx.x;
    int c = threadIdx.x & 255, hf = threadIdx.x >> 8;
    const float* W2d = W2 + (size_t)d * 512;
    const int h0 = hf * 256;
    float s0 = 0.f, s1 = 0.f;
    #pragma unroll 8
    for (int i = 0; i < 256; i += 2) {
        s0 += W2d[h0 + i]     * w_qkv[(size_t)(h0 + i) * 256 + c];
        s1 += W2d[h0 + i + 1] * w_qkv[(size_t)(h0 + i + 1) * 256 + c];
    }
    __shared__ float ps[512];
    __shared__ float red[256];
    ps[threadIdx.x] = s0 + s1;
    if (hf == 0) red[c] = W2d[c] * BE[c] + W2d[256 + c] * BE[256 + c];
    __syncthreads();
    if (hf == 0) {
        float s = ps[c] + ps[256 + c];
        W3B[(size_t)d * 256 + c] = f2bs(s * A[c]);
    }
    for (int off = 128; off > 0; off >>= 1) {
        if (hf == 0 && c < off) red[c] += red[c + off];
        __syncthreads();
    }
    if (threadIdx.x == 0) B3[d] = b_out[d] + red[0];
}

// ============ final GEMM: out = W3B @ xT + b3 ============
// grid 1024: m0 = (bid>>9)*128, chunk = bid&511 (XCD pairing). Wave owns 32 rows x 64 cols.
__global__ __launch_bounds__(256, 2) void k_final(const ushort_t* __restrict__ XT,
                                                  const ushort_t* __restrict__ W3B,
                                                  const float* __restrict__ B3,
                                                  float* __restrict__ out) {
    __shared__ __align__(16) ushort_t xs[64 * 264];
    const int tid  = threadIdx.x;
    const int lane = tid & 63;
    const int wv   = __builtin_amdgcn_readfirstlane(tid >> 6);
    const int ln   = lane & 15;
    const int q    = lane >> 4;
    const int m0   = (blockIdx.x >> 9) * 128;
    const int l0   = (blockIdx.x & 511) * 64;

    sfrag8 Af[2][8];
    #pragma unroll
    for (int mt = 0; mt < 2; mt++) {
        const ushort_t* ap = W3B + (size_t)(m0 + wv*32 + mt*16 + ln) * 256 + q*8;
        #pragma unroll
        for (int k0 = 0; k0 < 8; k0++) Af[mt][k0] = *(const sfrag8*)(ap + k0*32);
    }
    float bias[2][4];
    #pragma unroll
    for (int mt = 0; mt < 2; mt++)
        #pragma unroll
        for (int r = 0; r < 4; r++)
            bias[mt][r] = B3[m0 + wv*32 + mt*16 + q*4 + r];

    #pragma unroll
    for (int it = 0; it < 8; it++) {
        int idx = it * 256 + tid;
        int row = idx >> 5, seg = idx & 31;
        *(uint4*)&xs[row * 264 + seg * 8] =
            *(const uint4*)(XT + (size_t)(l0 + row) * 256 + seg * 8);
    }
    __syncthreads();

    f32x4 acc[2][4];
    #pragma unroll
    for (int mt = 0; mt < 2; mt++)
        #pragma unroll
        for (int nt = 0; nt < 4; nt++)
            #pragma unroll
            for (int e = 0; e < 4; e++) acc[mt][nt][e] = 0.f;

    #pragma unroll
    for (int k0 = 0; k0 < 8; k0++) {
        sfrag8 b0 = *(const sfrag8*)&xs[(0*16 + ln) * 264 + k0*32 + q*8];
        sfrag8 b1 = *(const sfrag8*)&xs[(1*16 + ln) * 264 + k0*32 + q*8];
        sfrag8 b2 = *(const sfrag8*)&xs[(2*16 + ln) * 264 + k0*32 + q*8];
        sfrag8 b3 = *(const sfrag8*)&xs[(3*16 + ln) * 264 + k0*32 + q*8];
        #pragma unroll
        for (int mt = 0; mt < 2; mt++) {
            acc[mt][0] = __builtin_amdgcn_mfma_f32_16x16x32_bf16(Af[mt][k0], b0, acc[mt][0], 0, 0, 0);
            acc[mt][1] = __builtin_amdgcn_mfma_f32_16x16x32_bf16(Af[mt][k0], b1, acc[mt][1], 0, 0, 0);
            acc[mt][2] = __builtin_amdgcn_mfma_f32_16x16x32_bf16(Af[mt][k0], b2, acc[mt][2], 0, 0, 0);
            acc[mt][3] = __builtin_amdgcn_mfma_f32_16x16x32_bf16(Af[mt][k0], b3, acc[mt][3], 0, 0, 0);
        }
    }

    #pragma unroll
    for (int mt = 0; mt < 2; mt++)
        #pragma unroll
        for (int nt = 0; nt < 4; nt++)
            #pragma unroll
            for (int r = 0; r < 4; r++) {
                int row = m0 + wv*32 + mt*16 + q*4 + r;
                int col = l0 + nt*16 + ln;
                out[(size_t)row * LSEQ + col] = acc[mt][nt][r] + bias[mt][r];
            }
}

// ============ launch ============
extern "C" void kernel_launch(void* const* d_in, const int* in_sizes, int n_in,
                              void* d_out, int out_size, void* d_ws, size_t ws_size,
                              hipStream_t stream) {
    const float* x     = (const float*)d_in[0];
    const float* gn_w  = (const float*)d_in[1];
    const float* gn_b  = (const float*)d_in[2];
    const float* w_qkv = (const float*)d_in[3];
    const float* b_qkv = (const float*)d_in[4];
    const float* w_out = (const float*)d_in[5];
    const float* b_out = (const float*)d_in[6];
    float* out = (float*)d_out;
    float* ws  = (float*)d_ws;

    float*    gsum   = ws + 0;        // 32
    float*    gsumsq = ws + 32;       // 32
    float*    S      = ws + 64;       // 32768
    float*    Z      = ws + 32832;    // 512   [zeroed through 33344]
    float*    A      = ws + 33344;    // 256
    float*    BB     = ws + 33600;    // 256
    float*    BE     = ws + 33856;    // 1536
    float*    BE2    = ws + 35392;    // 1024
    ushort_t* WEB    = (ushort_t*)(ws + 36416);    // 1024*256 bf16 (65536 f)
    float*    W2     = ws + 101952;   // 131072
    ushort_t* W3B    = (ushort_t*)(ws + 233024);   // 256*256 bf16 (32768 f)
    float*    B3     = ws + 265792;   // 256
    ushort_t* XT     = (ushort_t*)(ws + 266048);   // 32768*256 bf16 (4194304 f)

    hipMemsetAsync(ws, 0, 33344 * sizeof(float), stream);   // gsum, gsumsq, S, Z
    k_tr    <<<512,  256, 0, stream>>>(x, XT, gsum, gsumsq);
    k_ab    <<<1,    256, 0, stream>>>(gn_w, gn_b, gsum, gsumsq, A, BB);
    k_fold_b<<<6,    256, 0, stream>>>(w_qkv, b_qkv, BB, BE);
    k_fold_w<<<1024, 256, 0, stream>>>(w_qkv, A, BE, WEB, BE2);
    k_attn  <<<512,  512, 0, stream>>>(XT, WEB, BE2, S, Z);
    k_w2    <<<512,  256, 0, stream>>>(w_out, S, Z, W2);
    k_w3    <<<256,  512, 0, stream>>>(w_qkv, W2, A, BE, b_out, W3B, B3);
    k_final <<<1024, 256, 0, stream>>>(XT, W3B, B3, out);
}

// Round 3
// 198.205 us; speedup vs baseline: 1.4319x; 1.2505x over previous
//
#include <hip/hip_runtime.h>
#include <hip/hip_bf16.h>

typedef unsigned short ushort_t;
typedef unsigned int uint_t;

#define DIM   256
#define LSEQ  32768
#define HEADS 8
#define CPG   8
#define EPS   1e-5f

typedef float f32x4 __attribute__((ext_vector_type(4)));
typedef short sfrag8 __attribute__((ext_vector_type(8)));

static __device__ __forceinline__ float b2f(ushort_t u) {
    return __uint_as_float((uint_t)u << 16);
}
static __device__ __forceinline__ ushort_t f2bs(float f) {
    union { __hip_bfloat16 h; ushort_t u; } cv;
    cv.h = __float2bfloat16(f);
    return cv.u;
}
static __device__ __forceinline__ uint_t pk2(float a, float b) {
    return (uint_t)f2bs(a) | ((uint_t)f2bs(b) << 16);
}
static __device__ __forceinline__ void glds16(const ushort_t* g, ushort_t* l) {
    __builtin_amdgcn_global_load_lds((const __attribute__((address_space(1))) uint_t*)g,
                                     (__attribute__((address_space(3))) uint_t*)l, 16, 0, 0);
}

// ============ fused transpose + group stats: pure-register 4x4 micro-transpose ============
__global__ __launch_bounds__(256) void k_tr(const float* __restrict__ x,
                                            ushort_t* __restrict__ XT,
                                            float* __restrict__ gsum,
                                            float* __restrict__ gsumsq) {
    const int tid   = threadIdx.x;
    const int lane  = tid & 63;
    const int wv    = tid >> 6;
    const int l_blk = lane >> 3;
    const int c_blk = lane & 7;
    const int c0    = (blockIdx.x & 1) * 128;
    const int l0b   = (blockIdx.x >> 1) * 128;
    const int cb    = c0 + 32 * wv + 4 * c_blk;

    const float* xr0 = x + (size_t)(cb + 0) * LSEQ;
    const float* xr1 = x + (size_t)(cb + 1) * LSEQ;
    const float* xr2 = x + (size_t)(cb + 2) * LSEQ;
    const float* xr3 = x + (size_t)(cb + 3) * LSEQ;

    float s = 0.f, s2 = 0.f;

    #pragma unroll
    for (int t = 0; t < 4; t++) {
        const int l = l0b + 32 * t + 4 * l_blk;
        float4 a = *(const float4*)(xr0 + l);
        float4 b = *(const float4*)(xr1 + l);
        float4 c = *(const float4*)(xr2 + l);
        float4 d = *(const float4*)(xr3 + l);

        s  += (a.x + a.y + a.z + a.w) + (b.x + b.y + b.z + b.w)
            + (c.x + c.y + c.z + c.w) + (d.x + d.y + d.z + d.w);
        s2 += (a.x*a.x + a.y*a.y + a.z*a.z + a.w*a.w)
            + (b.x*b.x + b.y*b.y + b.z*b.z + b.w*b.w)
            + (c.x*c.x + c.y*c.y + c.z*c.z + c.w*c.w)
            + (d.x*d.x + d.y*d.y + d.z*d.z + d.w*d.w);

        ushort_t* dst = XT + (size_t)l * 256 + cb;
        uint2 p0; p0.x = pk2(a.x, b.x); p0.y = pk2(c.x, d.x);
        uint2 p1; p1.x = pk2(a.y, b.y); p1.y = pk2(c.y, d.y);
        uint2 p2; p2.x = pk2(a.z, b.z); p2.y = pk2(c.z, d.z);
        uint2 p3; p3.x = pk2(a.w, b.w); p3.y = pk2(c.w, d.w);
        *(uint2*)(dst)           = p0;
        *(uint2*)(dst + 256)     = p1;
        *(uint2*)(dst + 512)     = p2;
        *(uint2*)(dst + 768)     = p3;
    }

    s  += __shfl_xor(s, 1);   s2 += __shfl_xor(s2, 1);
    s  += __shfl_xor(s, 8);   s2 += __shfl_xor(s2, 8);
    s  += __shfl_xor(s, 16);  s2 += __shfl_xor(s2, 16);
    s  += __shfl_xor(s, 32);  s2 += __shfl_xor(s2, 32);
    if (l_blk == 0 && (c_blk & 1) == 0) {
        int g = ((c0 + 32 * wv) >> 3) + (c_blk >> 1);
        atomicAdd(&gsum[g], s);
        atomicAdd(&gsumsq[g], s2);
    }
}

// ============ a[c], bb[c] ============
__global__ void k_ab(const float* __restrict__ gn_w, const float* __restrict__ gn_b,
                     const float* __restrict__ gsum, const float* __restrict__ gsumsq,
                     float* __restrict__ A, float* __restrict__ BB) {
    int c = threadIdx.x;
    int g = c >> 3;
    const float inv_n = 1.f / (float)(CPG * LSEQ);
    float mu  = gsum[g] * inv_n;
    float var = gsumsq[g] * inv_n - mu * mu;
    float inv = rsqrtf(var + EPS);
    float a = gn_w[c] * inv;
    A[c]  = a;
    BB[c] = gn_b[c] - mu * a;
}

// ============ folded qkv biases ============
__global__ void k_fold_b(const float* __restrict__ w_qkv, const float* __restrict__ b_qkv,
                         const float* __restrict__ BB, float* __restrict__ BE) {
    int r = blockIdx.x * 256 + threadIdx.x;   // 1536
    float s = b_qkv[r];
    const float4* wr = (const float4*)(w_qkv + (size_t)r * DIM);
    const float4* bb = (const float4*)BB;
    #pragma unroll 4
    for (int c4 = 0; c4 < 64; c4++) {
        float4 w = wr[c4], b = bb[c4];
        s += w.x*b.x + w.y*b.y + w.z*b.z + w.w*b.w;
    }
    BE[r] = s;
}

// ============ folded k/v weights: WEB bf16 [r'][c], r' = h*128 + part*64 + j ============
__global__ void k_fold_w(const float* __restrict__ w_qkv, const float* __restrict__ A,
                         const float* __restrict__ BE,
                         ushort_t* __restrict__ WEB, float* __restrict__ BE2) {
    int idx = blockIdx.x * 256 + threadIdx.x;   // 262144
    int rp = idx >> 8, c = idx & 255;
    int h = rp >> 7, sub = rp & 127, part = sub >> 6, j = sub & 63;
    int orig = 512 + part * 512 + h * 64 + j;
    WEB[(size_t)rp * 256 + c] = f2bs(w_qkv[(size_t)orig * 256 + c] * A[c]);
    if (c == 0) BE2[rp] = BE[orig];
}

// ============ fused kv-GEMM + exp + context GEMM (v4) ============
// Geometry: grid 512 x 256 threads (4 waves). h = bid>>6, superchunk = bid&63
// (512 cols amortize Af loads + S atomics; sharers differ by 64 == 0 mod 8 -> same XCD L2).
// 16 chunks of 32 cols. Wave wv: mh=wv>>1 (0: K rows -> ek, 1: V rows -> vv),
// ms=(wv&1)*32 row-offset. Af[2][8]=64 VGPRs -- the only size the allocator has ever
// kept resident (r0: 88-VGPR alloc OK'd 2mt; r2: 4mt got reloaded from L2 every iter).
// LDS: dbuf xs 2x16KB + ek/vv 2x5KB = 42.25KB -> 3 blocks/CU.
// Staging: global_load_lds w16 direct, source-granule XOR-swizzle (g ^ (row&7));
// counted vmcnt(4): chunk t+1 issued at top of iter t, waited one full iter later.
// Barriers: X = vmcnt(4)+lgkm(0) (xs[t] staged, prev GEMM2 reads drained);
// Y = lgkm(0) (ek/vv visible). Never vmcnt(0) on fresh loads (r1/r2 lesson).
__global__ __launch_bounds__(256, 2) void k_attn(const ushort_t* __restrict__ XT,
                                                 const ushort_t* __restrict__ WEB,
                                                 const float* __restrict__ BE2,
                                                 float* __restrict__ S, float* __restrict__ Z) {
    __shared__ __align__(16) ushort_t xs[2][32 * 256];
    __shared__ __align__(16) ushort_t ek[64 * 40];
    __shared__ __align__(16) ushort_t vv[64 * 40];
    const int tid  = threadIdx.x;
    const int lane = tid & 63;
    const int wv   = __builtin_amdgcn_readfirstlane(tid >> 6);
    const int ln   = lane & 15;
    const int q    = lane >> 4;
    const int mh   = wv >> 1;          // 0: ek (K rows), 1: vv (V rows)
    const int ms   = (wv & 1) * 32;    // row offset inside the 64-row half
    const int h    = blockIdx.x >> 6;
    const int cg0  = (blockIdx.x & 63) * 512;

    const int srow = lane >> 5;        // which of the 2 rows this glds covers
    const int sg   = lane & 31;        // 16B granule within a 512B row

    // A fragments: 32 weight rows x K=256 -> Af[2][8] = 64 VGPRs (stays resident)
    sfrag8 Af[2][8];
    #pragma unroll
    for (int mt = 0; mt < 2; mt++) {
        const ushort_t* ap = WEB + (size_t)(h*128 + mh*64 + ms + mt*16 + ln) * 256 + q*8;
        #pragma unroll
        for (int k0 = 0; k0 < 8; k0++) Af[mt][k0] = *(const sfrag8*)(ap + k0*32);
    }
    float bias[2][4];
    #pragma unroll
    for (int mt = 0; mt < 2; mt++)
        #pragma unroll
        for (int r = 0; r < 4; r++)
            bias[mt][r] = BE2[h*128 + mh*64 + ms + mt*16 + q*4 + r];

    f32x4 Sacc[4];
    #pragma unroll
    for (int nt = 0; nt < 4; nt++)
        #pragma unroll
        for (int e = 0; e < 4; e++) Sacc[nt][e] = 0.f;
    float zp[8];
    #pragma unroll
    for (int i = 0; i < 8; i++) zp[i] = 0.f;

    // stage chunk 0 into buffer 0 (32 rows; each wave 8 rows, 4 glds/thread)
    #pragma unroll
    for (int kk = 0; kk < 4; kk++) {
        const int row = wv*8 + kk*2 + srow;
        glds16(XT + (size_t)(cg0 + row) * 256 + ((sg ^ (row & 7)) << 3),
               &xs[0][(wv*8 + kk*2) * 256]);
    }

    for (int t = 0; t < 16; t++) {
        const ushort_t* xb = xs[t & 1];

        if (t < 15) {   // issue chunk t+1 into the other buffer (waited next iter)
            const int l0n = cg0 + (t + 1) * 32;
            #pragma unroll
            for (int kk = 0; kk < 4; kk++) {
                const int row = wv*8 + kk*2 + srow;
                glds16(XT + (size_t)(l0n + row) * 256 + ((sg ^ (row & 7)) << 3),
                       &xs[(t + 1) & 1][(wv*8 + kk*2) * 256]);
            }
            asm volatile("s_waitcnt vmcnt(4) lgkmcnt(0)" ::: "memory");
        } else {
            asm volatile("s_waitcnt vmcnt(0) lgkmcnt(0)" ::: "memory");
        }
        __builtin_amdgcn_s_barrier();   // X: xs[t&1] staged everywhere

        // GEMM1: 32 weight rows (2 mt) x 32 cols (2 nt), K=256
        f32x4 acc[2][2];
        #pragma unroll
        for (int mt = 0; mt < 2; mt++)
            #pragma unroll
            for (int nt = 0; nt < 2; nt++)
                #pragma unroll
                for (int e = 0; e < 4; e++) acc[mt][nt][e] = 0.f;

        #pragma unroll
        for (int k0 = 0; k0 < 8; k0++) {
            sfrag8 b0 = *(const sfrag8*)&xb[(0*16 + ln) * 256 + (((k0*4 + q) ^ (ln & 7)) << 3)];
            sfrag8 b1 = *(const sfrag8*)&xb[(1*16 + ln) * 256 + (((k0*4 + q) ^ (ln & 7)) << 3)];
            #pragma unroll
            for (int mt = 0; mt < 2; mt++) {
                acc[mt][0] = __builtin_amdgcn_mfma_f32_16x16x32_bf16(Af[mt][k0], b0, acc[mt][0], 0, 0, 0);
                acc[mt][1] = __builtin_amdgcn_mfma_f32_16x16x32_bf16(Af[mt][k0], b1, acc[mt][1], 0, 0, 0);
            }
        }

        // ek (exp + register z-partials) / vv writes (pitch 40 -> ~2-way max conflict)
        if (mh == 0) {
            #pragma unroll
            for (int mt = 0; mt < 2; mt++)
                #pragma unroll
                for (int nt = 0; nt < 2; nt++)
                    #pragma unroll
                    for (int r = 0; r < 4; r++) {
                        int row = ms + mt*16 + q*4 + r;
                        float e = __expf(acc[mt][nt][r] + bias[mt][r]);
                        ek[row * 40 + nt*16 + ln] = f2bs(e);
                        zp[mt*4 + r] += e;
                    }
        } else {
            #pragma unroll
            for (int mt = 0; mt < 2; mt++)
                #pragma unroll
                for (int nt = 0; nt < 2; nt++)
                    #pragma unroll
                    for (int r = 0; r < 4; r++) {
                        int row = ms + mt*16 + q*4 + r;
                        vv[row * 40 + nt*16 + ln] = f2bs(acc[mt][nt][r] + bias[mt][r]);
                    }
        }
        asm volatile("s_waitcnt lgkmcnt(0)" ::: "memory");
        __builtin_amdgcn_s_barrier();   // Y: ek/vv visible

        // GEMM2: S += ek @ vv^T (K=32, single k-step). Wave owns S rows wv*16..+16.
        {
            sfrag8 a = *(const sfrag8*)&ek[(wv*16 + ln) * 40 + q*8];
            #pragma unroll
            for (int nt = 0; nt < 4; nt++) {
                sfrag8 b = *(const sfrag8*)&vv[(nt*16 + ln) * 40 + q*8];
                Sacc[nt] = __builtin_amdgcn_mfma_f32_16x16x32_bf16(a, b, Sacc[nt], 0, 0, 0);
            }
        }
    }

    float* Sh = S + h * 4096;
    #pragma unroll
    for (int nt = 0; nt < 4; nt++)
        #pragma unroll
        for (int r = 0; r < 4; r++)
            atomicAdd(&Sh[(wv*16 + q*4 + r) * 64 + nt*16 + ln], Sacc[nt][r]);

    if (mh == 0) {
        #pragma unroll
        for (int i = 0; i < 8; i++) {
            float z = zp[i];
            z += __shfl_xor(z, 1);
            z += __shfl_xor(z, 2);
            z += __shfl_xor(z, 4);
            z += __shfl_xor(z, 8);
            if (ln == 0) {
                int row = ms + (i >> 2)*16 + q*4 + (i & 3);
                atomicAdd(&Z[h*64 + row], z);
            }
        }
    }
}

// ============ W2[d][hc] = sum_e w_out[d][h64+e] * S[hc][e] / Z[hc] ============
__global__ void k_w2(const float* __restrict__ w_out, const float* __restrict__ S,
                     const float* __restrict__ Z, float* __restrict__ W2) {
    int d  = blockIdx.x >> 1;
    int hc = ((blockIdx.x & 1) << 8) + threadIdx.x;
    int h64 = hc & ~63;
    float invZ = 1.f / Z[hc];
    const float4* wo = (const float4*)(w_out + (size_t)d * 512 + h64);
    const float4* Sr = (const float4*)(S + (size_t)hc * 64);
    float s = 0.f;
    #pragma unroll
    for (int e4 = 0; e4 < 16; e4++) {
        float4 a = wo[e4], b = Sr[e4];
        s += a.x*b.x + a.y*b.y + a.z*b.z + a.w*b.w;
    }
    W2[(size_t)d * 512 + hc] = s * invZ;
}

// ============ W3B[d][c] bf16 + B3[d]: 512 threads, hc split across 2 halves ============
__global__ void k_w3(const float* __restrict__ w_qkv, const float* __restrict__ W2,
                     const float* __restrict__ A, const float* __restrict__ BE,
                     const float* __restrict__ b_out,
                     ushort_t* __restrict__ W3B, float* __restrict__ B3) {
    int d = blockIdx.x;
    int c = threadIdx.x & 255, hf = threadIdx.x >> 8;
    const float* W2d = W2 + (size_t)d * 512;
    const int h0 = hf * 256;
    float s0 = 0.f, s1 = 0.f;
    #pragma unroll 8
    for (int i = 0; i < 256; i += 2) {
        s0 += W2d[h0 + i]     * w_qkv[(size_t)(h0 + i) * 256 + c];
        s1 += W2d[h0 + i + 1] * w_qkv[(size_t)(h0 + i + 1) * 256 + c];
    }
    __shared__ float ps[512];
    __shared__ float red[256];
    ps[threadIdx.x] = s0 + s1;
    if (hf == 0) red[c] = W2d[c] * BE[c] + W2d[256 + c] * BE[256 + c];
    __syncthreads();
    if (hf == 0) {
        float s = ps[c] + ps[256 + c];
        W3B[(size_t)d * 256 + c] = f2bs(s * A[c]);
    }
    for (int off = 128; off > 0; off >>= 1) {
        if (hf == 0 && c < off) red[c] += red[c + off];
        __syncthreads();
    }
    if (threadIdx.x == 0) B3[d] = b_out[d] + red[0];
}

// ============ final GEMM: out = W3B @ xT + b3 ============
// grid 1024: m0 = (bid>>9)*128, chunk = bid&511 (XCD pairing). Wave owns 32 rows x 64 cols.
__global__ __launch_bounds__(256, 2) void k_final(const ushort_t* __restrict__ XT,
                                                  const ushort_t* __restrict__ W3B,
                                                  const float* __restrict__ B3,
                                                  float* __restrict__ out) {
    __shared__ __align__(16) ushort_t xs[64 * 264];
    const int tid  = threadIdx.x;
    const int lane = tid & 63;
    const int wv   = __builtin_amdgcn_readfirstlane(tid >> 6);
    const int ln   = lane & 15;
    const int q    = lane >> 4;
    const int m0   = (blockIdx.x >> 9) * 128;
    const int l0   = (blockIdx.x & 511) * 64;

    sfrag8 Af[2][8];
    #pragma unroll
    for (int mt = 0; mt < 2; mt++) {
        const ushort_t* ap = W3B + (size_t)(m0 + wv*32 + mt*16 + ln) * 256 + q*8;
        #pragma unroll
        for (int k0 = 0; k0 < 8; k0++) Af[mt][k0] = *(const sfrag8*)(ap + k0*32);
    }
    float bias[2][4];
    #pragma unroll
    for (int mt = 0; mt < 2; mt++)
        #pragma unroll
        for (int r = 0; r < 4; r++)
            bias[mt][r] = B3[m0 + wv*32 + mt*16 + q*4 + r];

    #pragma unroll
    for (int it = 0; it < 8; it++) {
        int idx = it * 256 + tid;
        int row = idx >> 5, seg = idx & 31;
        *(uint4*)&xs[row * 264 + seg * 8] =
            *(const uint4*)(XT + (size_t)(l0 + row) * 256 + seg * 8);
    }
    __syncthreads();

    f32x4 acc[2][4];
    #pragma unroll
    for (int mt = 0; mt < 2; mt++)
        #pragma unroll
        for (int nt = 0; nt < 4; nt++)
            #pragma unroll
            for (int e = 0; e < 4; e++) acc[mt][nt][e] = 0.f;

    #pragma unroll
    for (int k0 = 0; k0 < 8; k0++) {
        sfrag8 b0 = *(const sfrag8*)&xs[(0*16 + ln) * 264 + k0*32 + q*8];
        sfrag8 b1 = *(const sfrag8*)&xs[(1*16 + ln) * 264 + k0*32 + q*8];
        sfrag8 b2 = *(const sfrag8*)&xs[(2*16 + ln) * 264 + k0*32 + q*8];
        sfrag8 b3 = *(const sfrag8*)&xs[(3*16 + ln) * 264 + k0*32 + q*8];
        #pragma unroll
        for (int mt = 0; mt < 2; mt++) {
            acc[mt][0] = __builtin_amdgcn_mfma_f32_16x16x32_bf16(Af[mt][k0], b0, acc[mt][0], 0, 0, 0);
            acc[mt][1] = __builtin_amdgcn_mfma_f32_16x16x32_bf16(Af[mt][k0], b1, acc[mt][1], 0, 0, 0);
            acc[mt][2] = __builtin_amdgcn_mfma_f32_16x16x32_bf16(Af[mt][k0], b2, acc[mt][2], 0, 0, 0);
            acc[mt][3] = __builtin_amdgcn_mfma_f32_16x16x32_bf16(Af[mt][k0], b3, acc[mt][3], 0, 0, 0);
        }
    }

    #pragma unroll
    for (int mt = 0; mt < 2; mt++)
        #pragma unroll
        for (int nt = 0; nt < 4; nt++)
            #pragma unroll
            for (int r = 0; r < 4; r++) {
                int row = m0 + wv*32 + mt*16 + q*4 + r;
                int col = l0 + nt*16 + ln;
                out[(size_t)row * LSEQ + col] = acc[mt][nt][r] + bias[mt][r];
            }
}

// ============ launch ============
extern "C" void kernel_launch(void* const* d_in, const int* in_sizes, int n_in,
                              void* d_out, int out_size, void* d_ws, size_t ws_size,
                              hipStream_t stream) {
    const float* x     = (const float*)d_in[0];
    const float* gn_w  = (const float*)d_in[1];
    const float* gn_b  = (const float*)d_in[2];
    const float* w_qkv = (const float*)d_in[3];
    const float* b_qkv = (const float*)d_in[4];
    const float* w_out = (const float*)d_in[5];
    const float* b_out = (const float*)d_in[6];
    float* out = (float*)d_out;
    float* ws  = (float*)d_ws;

    float*    gsum   = ws + 0;        // 32
    float*    gsumsq = ws + 32;       // 32
    float*    S      = ws + 64;       // 32768
    float*    Z      = ws + 32832;    // 512   [zeroed through 33344]
    float*    A      = ws + 33344;    // 256
    float*    BB     = ws + 33600;    // 256
    float*    BE     = ws + 33856;    // 1536
    float*    BE2    = ws + 35392;    // 1024
    ushort_t* WEB    = (ushort_t*)(ws + 36416);    // 1024*256 bf16 (65536 f)
    float*    W2     = ws + 101952;   // 131072
    ushort_t* W3B    = (ushort_t*)(ws + 233024);   // 256*256 bf16 (32768 f)
    float*    B3     = ws + 265792;   // 256
    ushort_t* XT     = (ushort_t*)(ws + 266048);   // 32768*256 bf16 (4194304 f)

    hipMemsetAsync(ws, 0, 33344 * sizeof(float), stream);   // gsum, gsumsq, S, Z
    k_tr    <<<512,  256, 0, stream>>>(x, XT, gsum, gsumsq);
    k_ab    <<<1,    256, 0, stream>>>(gn_w, gn_b, gsum, gsumsq, A, BB);
    k_fold_b<<<6,    256, 0, stream>>>(w_qkv, b_qkv, BB, BE);
    k_fold_w<<<1024, 256, 0, stream>>>(w_qkv, A, BE, WEB, BE2);
    k_attn  <<<512,  256, 0, stream>>>(XT, WEB, BE2, S, Z);
    k_w2    <<<512,  256, 0, stream>>>(w_out, S, Z, W2);
    k_w3    <<<256,  512, 0, stream>>>(w_qkv, W2, A, BE, b_out, W3B, B3);
    k_final <<<1024, 256, 0, stream>>>(XT, W3B, B3, out);
}

// Round 4
// 184.496 us; speedup vs baseline: 1.5383x; 1.0743x over previous
//
#include <hip/hip_runtime.h>
#include <hip/hip_bf16.h>

typedef unsigned short ushort_t;
typedef unsigned int uint_t;

#define DIM   256
#define LSEQ  32768
#define HEADS 8
#define CPG   8
#define EPS   1e-5f

typedef float f32x4 __attribute__((ext_vector_type(4)));
typedef short sfrag8 __attribute__((ext_vector_type(8)));

static __device__ __forceinline__ ushort_t f2bs(float f) {
    union { __hip_bfloat16 h; ushort_t u; } cv;
    cv.h = __float2bfloat16(f);
    return cv.u;
}
static __device__ __forceinline__ uint_t pk2(float a, float b) {
    return (uint_t)f2bs(a) | ((uint_t)f2bs(b) << 16);
}
static __device__ __forceinline__ void glds16(const ushort_t* g, ushort_t* l) {
    __builtin_amdgcn_global_load_lds((const __attribute__((address_space(1))) uint_t*)g,
                                     (__attribute__((address_space(3))) uint_t*)l, 16, 0, 0);
}

// ============ fused transpose + group stats: pure-register 4x4 micro-transpose ============
__global__ __launch_bounds__(256) void k_tr(const float* __restrict__ x,
                                            ushort_t* __restrict__ XT,
                                            float* __restrict__ gsum,
                                            float* __restrict__ gsumsq) {
    const int tid   = threadIdx.x;
    const int lane  = tid & 63;
    const int wv    = tid >> 6;
    const int l_blk = lane >> 3;
    const int c_blk = lane & 7;
    const int c0    = (blockIdx.x & 1) * 128;
    const int l0b   = (blockIdx.x >> 1) * 128;
    const int cb    = c0 + 32 * wv + 4 * c_blk;

    const float* xr0 = x + (size_t)(cb + 0) * LSEQ;
    const float* xr1 = x + (size_t)(cb + 1) * LSEQ;
    const float* xr2 = x + (size_t)(cb + 2) * LSEQ;
    const float* xr3 = x + (size_t)(cb + 3) * LSEQ;

    float s = 0.f, s2 = 0.f;

    #pragma unroll
    for (int t = 0; t < 4; t++) {
        const int l = l0b + 32 * t + 4 * l_blk;
        float4 a = *(const float4*)(xr0 + l);
        float4 b = *(const float4*)(xr1 + l);
        float4 c = *(const float4*)(xr2 + l);
        float4 d = *(const float4*)(xr3 + l);

        s  += (a.x + a.y + a.z + a.w) + (b.x + b.y + b.z + b.w)
            + (c.x + c.y + c.z + c.w) + (d.x + d.y + d.z + d.w);
        s2 += (a.x*a.x + a.y*a.y + a.z*a.z + a.w*a.w)
            + (b.x*b.x + b.y*b.y + b.z*b.z + b.w*b.w)
            + (c.x*c.x + c.y*c.y + c.z*c.z + c.w*c.w)
            + (d.x*d.x + d.y*d.y + d.z*d.z + d.w*d.w);

        ushort_t* dst = XT + (size_t)l * 256 + cb;
        uint2 p0; p0.x = pk2(a.x, b.x); p0.y = pk2(c.x, d.x);
        uint2 p1; p1.x = pk2(a.y, b.y); p1.y = pk2(c.y, d.y);
        uint2 p2; p2.x = pk2(a.z, b.z); p2.y = pk2(c.z, d.z);
        uint2 p3; p3.x = pk2(a.w, b.w); p3.y = pk2(c.w, d.w);
        *(uint2*)(dst)           = p0;
        *(uint2*)(dst + 256)     = p1;
        *(uint2*)(dst + 512)     = p2;
        *(uint2*)(dst + 768)     = p3;
    }

    s  += __shfl_xor(s, 1);   s2 += __shfl_xor(s2, 1);
    s  += __shfl_xor(s, 8);   s2 += __shfl_xor(s2, 8);
    s  += __shfl_xor(s, 16);  s2 += __shfl_xor(s2, 16);
    s  += __shfl_xor(s, 32);  s2 += __shfl_xor(s2, 32);
    if (l_blk == 0 && (c_blk & 1) == 0) {
        int g = ((c0 + 32 * wv) >> 3) + (c_blk >> 1);
        atomicAdd(&gsum[g], s);
        atomicAdd(&gsumsq[g], s2);
    }
}

// ============ fused fold: A/BB recompute + BE (all 1536 rows) + WEB/BE2 (k/v rows)
//              + S/Z zeroing (blocks 0..129) ============
__global__ __launch_bounds__(256) void k_fold(const float* __restrict__ gn_w,
                                              const float* __restrict__ gn_b,
                                              const float* __restrict__ gsum,
                                              const float* __restrict__ gsumsq,
                                              const float* __restrict__ w_qkv,
                                              const float* __restrict__ b_qkv,
                                              ushort_t* __restrict__ WEB,
                                              float* __restrict__ BE,
                                              float* __restrict__ BE2,
                                              float* __restrict__ S,
                                              float* __restrict__ Z) {
    const int r = blockIdx.x;      // 1536 qkv rows
    const int c = threadIdx.x;     // 256 channels

    // zero S (32768 f, blocks 0..127) and Z (512 f, blocks 128..129)
    if (r < 128)      S[r * 256 + c] = 0.f;
    else if (r < 130) Z[(r - 128) * 256 + c] = 0.f;

    // per-thread groupnorm fold coefficients
    const int g = c >> 3;
    const float inv_n = 1.f / (float)(CPG * LSEQ);
    float mu  = gsum[g] * inv_n;
    float var = gsumsq[g] * inv_n - mu * mu;
    float a  = gn_w[c] * rsqrtf(var + EPS);
    float bb = gn_b[c] - mu * a;

    float w = w_qkv[(size_t)r * 256 + c];

    __shared__ float red[256];
    red[c] = w * bb;
    __syncthreads();
    for (int off = 128; off > 0; off >>= 1) {
        if (c < off) red[c] += red[c + off];
        __syncthreads();
    }
    float be = b_qkv[r] + red[0];
    if (c == 0) BE[r] = be;

    if (r >= 512) {   // k/v rows -> folded bf16 weights in attn layout
        int tt = r - 512;
        int part = tt >> 9, h = (tt >> 6) & 7, j = tt & 63;
        int rp = h * 128 + part * 64 + j;
        WEB[(size_t)rp * 256 + c] = f2bs(w * a);
        if (c == 0) BE2[rp] = be;
    }
}

// ============ fused kv-GEMM + exp + context GEMM (v4 structure + setprio) ============
// grid 512 x 256 threads (4 waves). h = bid>>6, superchunk = bid&63 (512 cols, 16 chunks
// of 32). Wave wv: mh=wv>>1 (0: K rows -> ek, 1: V rows -> vv), ms=(wv&1)*32.
// Af[2][8]=64 VGPRs (allocator-resident; r0/r2 established 4mt reloads from L2).
// LDS: dbuf xs 2x16KB + ek/vv 2x5KB = 42.25KB. Staging: global_load_lds w16 direct,
// source-granule XOR-swizzle (g ^ (row&7)); counted vmcnt(4) one iter deep.
// s_setprio(1) around MFMA clusters (T5: role-split waves).
__global__ __launch_bounds__(256, 2) void k_attn(const ushort_t* __restrict__ XT,
                                                 const ushort_t* __restrict__ WEB,
                                                 const float* __restrict__ BE2,
                                                 float* __restrict__ S, float* __restrict__ Z) {
    __shared__ __align__(16) ushort_t xs[2][32 * 256];
    __shared__ __align__(16) ushort_t ek[64 * 40];
    __shared__ __align__(16) ushort_t vv[64 * 40];
    const int tid  = threadIdx.x;
    const int lane = tid & 63;
    const int wv   = __builtin_amdgcn_readfirstlane(tid >> 6);
    const int ln   = lane & 15;
    const int q    = lane >> 4;
    const int mh   = wv >> 1;
    const int ms   = (wv & 1) * 32;
    const int h    = blockIdx.x >> 6;
    const int cg0  = (blockIdx.x & 63) * 512;

    const int srow = lane >> 5;
    const int sg   = lane & 31;

    sfrag8 Af[2][8];
    #pragma unroll
    for (int mt = 0; mt < 2; mt++) {
        const ushort_t* ap = WEB + (size_t)(h*128 + mh*64 + ms + mt*16 + ln) * 256 + q*8;
        #pragma unroll
        for (int k0 = 0; k0 < 8; k0++) Af[mt][k0] = *(const sfrag8*)(ap + k0*32);
    }
    float bias[2][4];
    #pragma unroll
    for (int mt = 0; mt < 2; mt++)
        #pragma unroll
        for (int r = 0; r < 4; r++)
            bias[mt][r] = BE2[h*128 + mh*64 + ms + mt*16 + q*4 + r];

    f32x4 Sacc[4];
    #pragma unroll
    for (int nt = 0; nt < 4; nt++)
        #pragma unroll
        for (int e = 0; e < 4; e++) Sacc[nt][e] = 0.f;
    float zp[8];
    #pragma unroll
    for (int i = 0; i < 8; i++) zp[i] = 0.f;

    #pragma unroll
    for (int kk = 0; kk < 4; kk++) {
        const int row = wv*8 + kk*2 + srow;
        glds16(XT + (size_t)(cg0 + row) * 256 + ((sg ^ (row & 7)) << 3),
               &xs[0][(wv*8 + kk*2) * 256]);
    }

    for (int t = 0; t < 16; t++) {
        const ushort_t* xb = xs[t & 1];

        if (t < 15) {
            const int l0n = cg0 + (t + 1) * 32;
            #pragma unroll
            for (int kk = 0; kk < 4; kk++) {
                const int row = wv*8 + kk*2 + srow;
                glds16(XT + (size_t)(l0n + row) * 256 + ((sg ^ (row & 7)) << 3),
                       &xs[(t + 1) & 1][(wv*8 + kk*2) * 256]);
            }
            asm volatile("s_waitcnt vmcnt(4) lgkmcnt(0)" ::: "memory");
        } else {
            asm volatile("s_waitcnt vmcnt(0) lgkmcnt(0)" ::: "memory");
        }
        __builtin_amdgcn_s_barrier();   // X: xs[t&1] staged

        f32x4 acc[2][2];
        #pragma unroll
        for (int mt = 0; mt < 2; mt++)
            #pragma unroll
            for (int nt = 0; nt < 2; nt++)
                #pragma unroll
                for (int e = 0; e < 4; e++) acc[mt][nt][e] = 0.f;

        __builtin_amdgcn_s_setprio(1);
        #pragma unroll
        for (int k0 = 0; k0 < 8; k0++) {
            sfrag8 b0 = *(const sfrag8*)&xb[(0*16 + ln) * 256 + (((k0*4 + q) ^ (ln & 7)) << 3)];
            sfrag8 b1 = *(const sfrag8*)&xb[(1*16 + ln) * 256 + (((k0*4 + q) ^ (ln & 7)) << 3)];
            #pragma unroll
            for (int mt = 0; mt < 2; mt++) {
                acc[mt][0] = __builtin_amdgcn_mfma_f32_16x16x32_bf16(Af[mt][k0], b0, acc[mt][0], 0, 0, 0);
                acc[mt][1] = __builtin_amdgcn_mfma_f32_16x16x32_bf16(Af[mt][k0], b1, acc[mt][1], 0, 0, 0);
            }
        }
        __builtin_amdgcn_s_setprio(0);

        if (mh == 0) {
            #pragma unroll
            for (int mt = 0; mt < 2; mt++)
                #pragma unroll
                for (int nt = 0; nt < 2; nt++)
                    #pragma unroll
                    for (int r = 0; r < 4; r++) {
                        int row = ms + mt*16 + q*4 + r;
                        float e = __expf(acc[mt][nt][r] + bias[mt][r]);
                        ek[row * 40 + nt*16 + ln] = f2bs(e);
                        zp[mt*4 + r] += e;
                    }
        } else {
            #pragma unroll
            for (int mt = 0; mt < 2; mt++)
                #pragma unroll
                for (int nt = 0; nt < 2; nt++)
                    #pragma unroll
                    for (int r = 0; r < 4; r++) {
                        int row = ms + mt*16 + q*4 + r;
                        vv[row * 40 + nt*16 + ln] = f2bs(acc[mt][nt][r] + bias[mt][r]);
                    }
        }
        asm volatile("s_waitcnt lgkmcnt(0)" ::: "memory");
        __builtin_amdgcn_s_barrier();   // Y: ek/vv visible

        {
            sfrag8 a = *(const sfrag8*)&ek[(wv*16 + ln) * 40 + q*8];
            __builtin_amdgcn_s_setprio(1);
            #pragma unroll
            for (int nt = 0; nt < 4; nt++) {
                sfrag8 b = *(const sfrag8*)&vv[(nt*16 + ln) * 40 + q*8];
                Sacc[nt] = __builtin_amdgcn_mfma_f32_16x16x32_bf16(a, b, Sacc[nt], 0, 0, 0);
            }
            __builtin_amdgcn_s_setprio(0);
        }
    }

    float* Sh = S + h * 4096;
    #pragma unroll
    for (int nt = 0; nt < 4; nt++)
        #pragma unroll
        for (int r = 0; r < 4; r++)
            atomicAdd(&Sh[(wv*16 + q*4 + r) * 64 + nt*16 + ln], Sacc[nt][r]);

    if (mh == 0) {
        #pragma unroll
        for (int i = 0; i < 8; i++) {
            float z = zp[i];
            z += __shfl_xor(z, 1);
            z += __shfl_xor(z, 2);
            z += __shfl_xor(z, 4);
            z += __shfl_xor(z, 8);
            if (ln == 0) {
                int row = ms + (i >> 2)*16 + q*4 + (i & 3);
                atomicAdd(&Z[h*64 + row], z);
            }
        }
    }
}

// ============ fused W2 (LDS) + W3B/B3: removes W2 global round-trip ============
__global__ __launch_bounds__(512) void k_w23(const float* __restrict__ w_out,
                                             const float* __restrict__ S,
                                             const float* __restrict__ Z,
                                             const float* __restrict__ w_qkv,
                                             const float* __restrict__ BE,
                                             const float* __restrict__ gn_w,
                                             const float* __restrict__ gsum,
                                             const float* __restrict__ gsumsq,
                                             const float* __restrict__ b_out,
                                             ushort_t* __restrict__ W3B,
                                             float* __restrict__ B3) {
    const int d = blockIdx.x;       // 256 output channels
    const int t = threadIdx.x;      // 512
    __shared__ float w2s[512];
    __shared__ float ps[512];
    __shared__ float red[256];

    // phase 1: W2 row d into LDS: w2s[hc] = dot(w_out[d][h64..], S[hc]) / Z[hc]
    {
        const int hc  = t;
        const int h64 = hc & ~63;
        float invZ = 1.f / Z[hc];
        const float4* wo = (const float4*)(w_out + (size_t)d * 512 + h64);
        const float4* Sr = (const float4*)(S + (size_t)hc * 64);
        float s = 0.f;
        #pragma unroll
        for (int e4 = 0; e4 < 16; e4++) {
            float4 a = wo[e4], b = Sr[e4];
            s += a.x*b.x + a.y*b.y + a.z*b.z + a.w*b.w;
        }
        w2s[hc] = s * invZ;
    }
    __syncthreads();

    // phase 2: W3B[d][c] = A[c] * sum_hc w2s[hc] * w_qkv[hc][c];  B3[d] = b_out[d] + w2s.BE
    const int c = t & 255, hf = t >> 8;
    const int h0 = hf * 256;
    float s0 = 0.f, s1 = 0.f;
    #pragma unroll 8
    for (int i = 0; i < 256; i += 2) {
        s0 += w2s[h0 + i]     * w_qkv[(size_t)(h0 + i) * 256 + c];
        s1 += w2s[h0 + i + 1] * w_qkv[(size_t)(h0 + i + 1) * 256 + c];
    }
    ps[t] = s0 + s1;
    if (hf == 0) red[c] = w2s[c] * BE[c] + w2s[256 + c] * BE[256 + c];
    __syncthreads();
    if (hf == 0) {
        const int g = c >> 3;
        const float inv_n = 1.f / (float)(CPG * LSEQ);
        float mu  = gsum[g] * inv_n;
        float var = gsumsq[g] * inv_n - mu * mu;
        float a = gn_w[c] * rsqrtf(var + EPS);
        W3B[(size_t)d * 256 + c] = f2bs((ps[c] + ps[256 + c]) * a);
    }
    for (int off = 128; off > 0; off >>= 1) {
        if (hf == 0 && c < off) red[c] += red[c + off];
        __syncthreads();
    }
    if (t == 0) B3[d] = b_out[d] + red[0];
}

// ============ final GEMM: out = W3B @ xT + b3 (glds staging + swizzle + setprio) ============
// grid 1024: m0 = (bid>>9)*128, chunk = bid&511. Wave owns 32 rows x 64 cols.
__global__ __launch_bounds__(256, 2) void k_final(const ushort_t* __restrict__ XT,
                                                  const ushort_t* __restrict__ W3B,
                                                  const float* __restrict__ B3,
                                                  float* __restrict__ out) {
    __shared__ __align__(16) ushort_t xs[64 * 256];
    const int tid  = threadIdx.x;
    const int lane = tid & 63;
    const int wv   = __builtin_amdgcn_readfirstlane(tid >> 6);
    const int ln   = lane & 15;
    const int q    = lane >> 4;
    const int m0   = (blockIdx.x >> 9) * 128;
    const int l0   = (blockIdx.x & 511) * 64;

    const int srow = lane >> 5;
    const int sg   = lane & 31;

    // stage 64 rows via global_load_lds w16, XOR-swizzled source granules
    #pragma unroll
    for (int kk = 0; kk < 8; kk++) {
        const int row = wv*16 + kk*2 + srow;
        glds16(XT + (size_t)(l0 + row) * 256 + ((sg ^ (row & 7)) << 3),
               &xs[(wv*16 + kk*2) * 256]);
    }

    sfrag8 Af[2][8];
    #pragma unroll
    for (int mt = 0; mt < 2; mt++) {
        const ushort_t* ap = W3B + (size_t)(m0 + wv*32 + mt*16 + ln) * 256 + q*8;
        #pragma unroll
        for (int k0 = 0; k0 < 8; k0++) Af[mt][k0] = *(const sfrag8*)(ap + k0*32);
    }
    float bias[2][4];
    #pragma unroll
    for (int mt = 0; mt < 2; mt++)
        #pragma unroll
        for (int r = 0; r < 4; r++)
            bias[mt][r] = B3[m0 + wv*32 + mt*16 + q*4 + r];

    asm volatile("s_waitcnt vmcnt(0)" ::: "memory");
    __builtin_amdgcn_s_barrier();

    f32x4 acc[2][4];
    #pragma unroll
    for (int mt = 0; mt < 2; mt++)
        #pragma unroll
        for (int nt = 0; nt < 4; nt++)
            #pragma unroll
            for (int e = 0; e < 4; e++) acc[mt][nt][e] = 0.f;

    __builtin_amdgcn_s_setprio(1);
    #pragma unroll
    for (int k0 = 0; k0 < 8; k0++) {
        const int gg0 = ((k0*4 + q) ^ (ln & 7)) << 3;
        sfrag8 b0 = *(const sfrag8*)&xs[(0*16 + ln) * 256 + gg0];
        sfrag8 b1 = *(const sfrag8*)&xs[(1*16 + ln) * 256 + gg0];
        sfrag8 b2 = *(const sfrag8*)&xs[(2*16 + ln) * 256 + gg0];
        sfrag8 b3 = *(const sfrag8*)&xs[(3*16 + ln) * 256 + gg0];
        #pragma unroll
        for (int mt = 0; mt < 2; mt++) {
            acc[mt][0] = __builtin_amdgcn_mfma_f32_16x16x32_bf16(Af[mt][k0], b0, acc[mt][0], 0, 0, 0);
            acc[mt][1] = __builtin_amdgcn_mfma_f32_16x16x32_bf16(Af[mt][k0], b1, acc[mt][1], 0, 0, 0);
            acc[mt][2] = __builtin_amdgcn_mfma_f32_16x16x32_bf16(Af[mt][k0], b2, acc[mt][2], 0, 0, 0);
            acc[mt][3] = __builtin_amdgcn_mfma_f32_16x16x32_bf16(Af[mt][k0], b3, acc[mt][3], 0, 0, 0);
        }
    }
    __builtin_amdgcn_s_setprio(0);

    #pragma unroll
    for (int mt = 0; mt < 2; mt++)
        #pragma unroll
        for (int nt = 0; nt < 4; nt++)
            #pragma unroll
            for (int r = 0; r < 4; r++) {
                int row = m0 + wv*32 + mt*16 + q*4 + r;
                int col = l0 + nt*16 + ln;
                out[(size_t)row * LSEQ + col] = acc[mt][nt][r] + bias[mt][r];
            }
}

// ============ launch ============
extern "C" void kernel_launch(void* const* d_in, const int* in_sizes, int n_in,
                              void* d_out, int out_size, void* d_ws, size_t ws_size,
                              hipStream_t stream) {
    const float* x     = (const float*)d_in[0];
    const float* gn_w  = (const float*)d_in[1];
    const float* gn_b  = (const float*)d_in[2];
    const float* w_qkv = (const float*)d_in[3];
    const float* b_qkv = (const float*)d_in[4];
    const float* w_out = (const float*)d_in[5];
    const float* b_out = (const float*)d_in[6];
    float* out = (float*)d_out;
    float* ws  = (float*)d_ws;

    float*    gsum   = ws + 0;        // 32
    float*    gsumsq = ws + 32;       // 32   [memset covers 64 floats]
    float*    S      = ws + 64;       // 32768 [zeroed by k_fold]
    float*    Z      = ws + 32832;    // 512   [zeroed by k_fold]
    float*    BE     = ws + 33856;    // 1536
    float*    BE2    = ws + 35392;    // 1024
    ushort_t* WEB    = (ushort_t*)(ws + 36416);    // 1024*256 bf16 (65536 f)
    ushort_t* W3B    = (ushort_t*)(ws + 233024);   // 256*256 bf16 (32768 f)
    float*    B3     = ws + 265792;   // 256
    ushort_t* XT     = (ushort_t*)(ws + 266048);   // 32768*256 bf16 (4194304 f)

    hipMemsetAsync(ws, 0, 64 * sizeof(float), stream);   // gsum, gsumsq only
    k_tr    <<<512,  256, 0, stream>>>(x, XT, gsum, gsumsq);
    k_fold  <<<1536, 256, 0, stream>>>(gn_w, gn_b, gsum, gsumsq, w_qkv, b_qkv,
                                       WEB, BE, BE2, S, Z);
    k_attn  <<<512,  256, 0, stream>>>(XT, WEB, BE2, S, Z);
    k_w23   <<<256,  512, 0, stream>>>(w_out, S, Z, w_qkv, BE, gn_w, gsum, gsumsq,
                                       b_out, W3B, B3);
    k_final <<<1024, 256, 0, stream>>>(XT, W3B, B3, out);
}

// Round 5
// 180.181 us; speedup vs baseline: 1.5752x; 1.0239x over previous
//
#include <hip/hip_runtime.h>
#include <hip/hip_bf16.h>

typedef unsigned short ushort_t;
typedef unsigned int uint_t;

#define DIM   256
#define LSEQ  32768
#define HEADS 8
#define CPG   8
#define EPS   1e-5f

typedef float f32x4 __attribute__((ext_vector_type(4)));
typedef short sfrag8 __attribute__((ext_vector_type(8)));

static __device__ __forceinline__ ushort_t f2bs(float f) {
    union { __hip_bfloat16 h; ushort_t u; } cv;
    cv.h = __float2bfloat16(f);
    return cv.u;
}
static __device__ __forceinline__ uint_t pk2(float a, float b) {
    return (uint_t)f2bs(a) | ((uint_t)f2bs(b) << 16);
}
static __device__ __forceinline__ void glds16(const ushort_t* g, ushort_t* l) {
    __builtin_amdgcn_global_load_lds((const __attribute__((address_space(1))) uint_t*)g,
                                     (__attribute__((address_space(3))) uint_t*)l, 16, 0, 0);
}

// ============ fused transpose + group stats: pure-register 4x4 micro-transpose ============
__global__ __launch_bounds__(256) void k_tr(const float* __restrict__ x,
                                            ushort_t* __restrict__ XT,
                                            float* __restrict__ gsum,
                                            float* __restrict__ gsumsq) {
    const int tid   = threadIdx.x;
    const int lane  = tid & 63;
    const int wv    = tid >> 6;
    const int l_blk = lane >> 3;
    const int c_blk = lane & 7;
    const int c0    = (blockIdx.x & 1) * 128;
    const int l0b   = (blockIdx.x >> 1) * 128;
    const int cb    = c0 + 32 * wv + 4 * c_blk;

    const float* xr0 = x + (size_t)(cb + 0) * LSEQ;
    const float* xr1 = x + (size_t)(cb + 1) * LSEQ;
    const float* xr2 = x + (size_t)(cb + 2) * LSEQ;
    const float* xr3 = x + (size_t)(cb + 3) * LSEQ;

    float s = 0.f, s2 = 0.f;

    #pragma unroll
    for (int t = 0; t < 4; t++) {
        const int l = l0b + 32 * t + 4 * l_blk;
        float4 a = *(const float4*)(xr0 + l);
        float4 b = *(const float4*)(xr1 + l);
        float4 c = *(const float4*)(xr2 + l);
        float4 d = *(const float4*)(xr3 + l);

        s  += (a.x + a.y + a.z + a.w) + (b.x + b.y + b.z + b.w)
            + (c.x + c.y + c.z + c.w) + (d.x + d.y + d.z + d.w);
        s2 += (a.x*a.x + a.y*a.y + a.z*a.z + a.w*a.w)
            + (b.x*b.x + b.y*b.y + b.z*b.z + b.w*b.w)
            + (c.x*c.x + c.y*c.y + c.z*c.z + c.w*c.w)
            + (d.x*d.x + d.y*d.y + d.z*d.z + d.w*d.w);

        ushort_t* dst = XT + (size_t)l * 256 + cb;
        uint2 p0; p0.x = pk2(a.x, b.x); p0.y = pk2(c.x, d.x);
        uint2 p1; p1.x = pk2(a.y, b.y); p1.y = pk2(c.y, d.y);
        uint2 p2; p2.x = pk2(a.z, b.z); p2.y = pk2(c.z, d.z);
        uint2 p3; p3.x = pk2(a.w, b.w); p3.y = pk2(c.w, d.w);
        *(uint2*)(dst)           = p0;
        *(uint2*)(dst + 256)     = p1;
        *(uint2*)(dst + 512)     = p2;
        *(uint2*)(dst + 768)     = p3;
    }

    s  += __shfl_xor(s, 1);   s2 += __shfl_xor(s2, 1);
    s  += __shfl_xor(s, 8);   s2 += __shfl_xor(s2, 8);
    s  += __shfl_xor(s, 16);  s2 += __shfl_xor(s2, 16);
    s  += __shfl_xor(s, 32);  s2 += __shfl_xor(s2, 32);
    if (l_blk == 0 && (c_blk & 1) == 0) {
        int g = ((c0 + 32 * wv) >> 3) + (c_blk >> 1);
        atomicAdd(&gsum[g], s);
        atomicAdd(&gsumsq[g], s2);
    }
}

// ============ fused fold: A/BB recompute + BE (all 1536 rows) + WEB/BE2 (k/v rows)
//              + S/Z zeroing (blocks 0..129) ============
__global__ __launch_bounds__(256) void k_fold(const float* __restrict__ gn_w,
                                              const float* __restrict__ gn_b,
                                              const float* __restrict__ gsum,
                                              const float* __restrict__ gsumsq,
                                              const float* __restrict__ w_qkv,
                                              const float* __restrict__ b_qkv,
                                              ushort_t* __restrict__ WEB,
                                              float* __restrict__ BE,
                                              float* __restrict__ BE2,
                                              float* __restrict__ S,
                                              float* __restrict__ Z) {
    const int r = blockIdx.x;      // 1536 qkv rows
    const int c = threadIdx.x;     // 256 channels

    // zero S (32768 f, blocks 0..127) and Z (512 f, blocks 128..129)
    if (r < 128)      S[r * 256 + c] = 0.f;
    else if (r < 130) Z[(r - 128) * 256 + c] = 0.f;

    // per-thread groupnorm fold coefficients
    const int g = c >> 3;
    const float inv_n = 1.f / (float)(CPG * LSEQ);
    float mu  = gsum[g] * inv_n;
    float var = gsumsq[g] * inv_n - mu * mu;
    float a  = gn_w[c] * rsqrtf(var + EPS);
    float bb = gn_b[c] - mu * a;

    float w = w_qkv[(size_t)r * 256 + c];

    __shared__ float red[256];
    red[c] = w * bb;
    __syncthreads();
    for (int off = 128; off > 0; off >>= 1) {
        if (c < off) red[c] += red[c + off];
        __syncthreads();
    }
    float be = b_qkv[r] + red[0];
    if (c == 0) BE[r] = be;

    if (r >= 512) {   // k/v rows -> folded bf16 weights in attn layout
        int tt = r - 512;
        int part = tt >> 9, h = (tt >> 6) & 7, j = tt & 63;
        int rp = h * 128 + part * 64 + j;
        WEB[(size_t)rp * 256 + c] = f2bs(w * a);
        if (c == 0) BE2[rp] = be;
    }
}

// ============ fused kv-GEMM + exp + context GEMM (v6: swapped-operand GEMM1) ============
// grid 512 x 256 threads (4 waves). h = bid>>6, superchunk = bid&63 (512 cols, 16 chunks
// of 32). Wave wv: mh=wv>>1 (0: K rows -> ek, 1: V rows -> vv), ms=(wv&1)*32.
// GEMM1 computes acc = mfma(xs_frag, Af, acc)  (operands SWAPPED: A/B lane layouts are
// identical, so D comes out transposed): lane's 4 acc regs = 4 consecutive SEQ positions
// at weight-channel wc = wt*16+ln. -> ek/vv writes become 4x ds_write_b64 (2-way banks,
// free) instead of 16x scalar ds_write_b16 (the 1.8M-conflict source since r0).
// ek/vv layout [kc][seq] pitch 40 unchanged -> GEMM2 reads stay single b128 frags.
// Af[2][8]=64 VGPRs (allocator-resident cap, r0/r2). LDS 42.25KB.
// Staging: global_load_lds w16 direct, source-granule XOR-swizzle (g ^ (row&7));
// counted vmcnt(4) one iter deep; never vmcnt(0) on fresh loads.
__global__ __launch_bounds__(256, 2) void k_attn(const ushort_t* __restrict__ XT,
                                                 const ushort_t* __restrict__ WEB,
                                                 const float* __restrict__ BE2,
                                                 float* __restrict__ S, float* __restrict__ Z) {
    __shared__ __align__(16) ushort_t xs[2][32 * 256];
    __shared__ __align__(16) ushort_t ek[64 * 40];
    __shared__ __align__(16) ushort_t vv[64 * 40];
    const int tid  = threadIdx.x;
    const int lane = tid & 63;
    const int wv   = __builtin_amdgcn_readfirstlane(tid >> 6);
    const int ln   = lane & 15;
    const int q    = lane >> 4;
    const int mh   = wv >> 1;
    const int ms   = (wv & 1) * 32;
    const int h    = blockIdx.x >> 6;
    const int cg0  = (blockIdx.x & 63) * 512;

    const int srow = lane >> 5;
    const int sg   = lane & 31;

    sfrag8 Af[2][8];
    #pragma unroll
    for (int mt = 0; mt < 2; mt++) {
        const ushort_t* ap = WEB + (size_t)(h*128 + mh*64 + ms + mt*16 + ln) * 256 + q*8;
        #pragma unroll
        for (int k0 = 0; k0 < 8; k0++) Af[mt][k0] = *(const sfrag8*)(ap + k0*32);
    }
    // bias indexed by weight-channel wc = wt*16+ln (swapped layout: wc follows ln)
    float bias2[2];
    #pragma unroll
    for (int wt = 0; wt < 2; wt++)
        bias2[wt] = BE2[h*128 + mh*64 + ms + wt*16 + ln];

    f32x4 Sacc[4];
    #pragma unroll
    for (int nt = 0; nt < 4; nt++)
        #pragma unroll
        for (int e = 0; e < 4; e++) Sacc[nt][e] = 0.f;
    float zp[2];
    zp[0] = 0.f; zp[1] = 0.f;

    #pragma unroll
    for (int kk = 0; kk < 4; kk++) {
        const int row = wv*8 + kk*2 + srow;
        glds16(XT + (size_t)(cg0 + row) * 256 + ((sg ^ (row & 7)) << 3),
               &xs[0][(wv*8 + kk*2) * 256]);
    }

    for (int t = 0; t < 16; t++) {
        const ushort_t* xb = xs[t & 1];

        if (t < 15) {
            const int l0n = cg0 + (t + 1) * 32;
            #pragma unroll
            for (int kk = 0; kk < 4; kk++) {
                const int row = wv*8 + kk*2 + srow;
                glds16(XT + (size_t)(l0n + row) * 256 + ((sg ^ (row & 7)) << 3),
                       &xs[(t + 1) & 1][(wv*8 + kk*2) * 256]);
            }
            asm volatile("s_waitcnt vmcnt(4) lgkmcnt(0)" ::: "memory");
        } else {
            asm volatile("s_waitcnt vmcnt(0) lgkmcnt(0)" ::: "memory");
        }
        __builtin_amdgcn_s_barrier();   // X: xs[t&1] staged

        // GEMM1 (swapped): acc[st][wt], D rows = seq (st*16 + q*4 + r), cols = wc (wt*16+ln)
        f32x4 acc[2][2];
        #pragma unroll
        for (int st = 0; st < 2; st++)
            #pragma unroll
            for (int wt = 0; wt < 2; wt++)
                #pragma unroll
                for (int e = 0; e < 4; e++) acc[st][wt][e] = 0.f;

        __builtin_amdgcn_s_setprio(1);
        #pragma unroll
        for (int k0 = 0; k0 < 8; k0++) {
            sfrag8 b0 = *(const sfrag8*)&xb[(0*16 + ln) * 256 + (((k0*4 + q) ^ (ln & 7)) << 3)];
            sfrag8 b1 = *(const sfrag8*)&xb[(1*16 + ln) * 256 + (((k0*4 + q) ^ (ln & 7)) << 3)];
            #pragma unroll
            for (int wt = 0; wt < 2; wt++) {
                acc[0][wt] = __builtin_amdgcn_mfma_f32_16x16x32_bf16(b0, Af[wt][k0], acc[0][wt], 0, 0, 0);
                acc[1][wt] = __builtin_amdgcn_mfma_f32_16x16x32_bf16(b1, Af[wt][k0], acc[1][wt], 0, 0, 0);
            }
        }
        __builtin_amdgcn_s_setprio(0);

        // packed b64 writes: 4 consecutive seq per lane at row kc = ms + wt*16 + ln
        if (mh == 0) {
            #pragma unroll
            for (int st = 0; st < 2; st++)
                #pragma unroll
                for (int wt = 0; wt < 2; wt++) {
                    float e0 = __expf(acc[st][wt][0] + bias2[wt]);
                    float e1 = __expf(acc[st][wt][1] + bias2[wt]);
                    float e2 = __expf(acc[st][wt][2] + bias2[wt]);
                    float e3 = __expf(acc[st][wt][3] + bias2[wt]);
                    zp[wt] += (e0 + e1) + (e2 + e3);
                    uint2 p; p.x = pk2(e0, e1); p.y = pk2(e2, e3);
                    *(uint2*)&ek[(ms + wt*16 + ln) * 40 + st*16 + q*4] = p;
                }
        } else {
            #pragma unroll
            for (int st = 0; st < 2; st++)
                #pragma unroll
                for (int wt = 0; wt < 2; wt++) {
                    uint2 p;
                    p.x = pk2(acc[st][wt][0] + bias2[wt], acc[st][wt][1] + bias2[wt]);
                    p.y = pk2(acc[st][wt][2] + bias2[wt], acc[st][wt][3] + bias2[wt]);
                    *(uint2*)&vv[(ms + wt*16 + ln) * 40 + st*16 + q*4] = p;
                }
        }
        asm volatile("s_waitcnt lgkmcnt(0)" ::: "memory");
        __builtin_amdgcn_s_barrier();   // Y: ek/vv visible

        // GEMM2: S += ek @ vv^T (K=32, single k-step). Wave owns S rows wv*16..+16.
        {
            sfrag8 a = *(const sfrag8*)&ek[(wv*16 + ln) * 40 + q*8];
            __builtin_amdgcn_s_setprio(1);
            #pragma unroll
            for (int nt = 0; nt < 4; nt++) {
                sfrag8 b = *(const sfrag8*)&vv[(nt*16 + ln) * 40 + q*8];
                Sacc[nt] = __builtin_amdgcn_mfma_f32_16x16x32_bf16(a, b, Sacc[nt], 0, 0, 0);
            }
            __builtin_amdgcn_s_setprio(0);
        }
    }

    float* Sh = S + h * 4096;
    #pragma unroll
    for (int nt = 0; nt < 4; nt++)
        #pragma unroll
        for (int r = 0; r < 4; r++)
            atomicAdd(&Sh[(wv*16 + q*4 + r) * 64 + nt*16 + ln], Sacc[nt][r]);

    // Z: zp[wt] is full seq-sum for kc = ms + wt*16 + ln within this wave's q-slice;
    // reduce across q-groups (lanes with same ln), then lanes 0..15 write.
    if (mh == 0) {
        #pragma unroll
        for (int wt = 0; wt < 2; wt++) {
            float z = zp[wt];
            z += __shfl_xor(z, 16);
            z += __shfl_xor(z, 32);
            if (lane < 16)
                atomicAdd(&Z[h*64 + ms + wt*16 + ln], z);
        }
    }
}

// ============ fused W2 (LDS) + W3B/B3: removes W2 global round-trip ============
__global__ __launch_bounds__(512) void k_w23(const float* __restrict__ w_out,
                                             const float* __restrict__ S,
                                             const float* __restrict__ Z,
                                             const float* __restrict__ w_qkv,
                                             const float* __restrict__ BE,
                                             const float* __restrict__ gn_w,
                                             const float* __restrict__ gsum,
                                             const float* __restrict__ gsumsq,
                                             const float* __restrict__ b_out,
                                             ushort_t* __restrict__ W3B,
                                             float* __restrict__ B3) {
    const int d = blockIdx.x;       // 256 output channels
    const int t = threadIdx.x;      // 512
    __shared__ float w2s[512];
    __shared__ float ps[512];
    __shared__ float red[256];

    // phase 1: W2 row d into LDS: w2s[hc] = dot(w_out[d][h64..], S[hc]) / Z[hc]
    {
        const int hc  = t;
        const int h64 = hc & ~63;
        float invZ = 1.f / Z[hc];
        const float4* wo = (const float4*)(w_out + (size_t)d * 512 + h64);
        const float4* Sr = (const float4*)(S + (size_t)hc * 64);
        float s = 0.f;
        #pragma unroll
        for (int e4 = 0; e4 < 16; e4++) {
            float4 a = wo[e4], b = Sr[e4];
            s += a.x*b.x + a.y*b.y + a.z*b.z + a.w*b.w;
        }
        w2s[hc] = s * invZ;
    }
    __syncthreads();

    // phase 2: W3B[d][c] = A[c] * sum_hc w2s[hc] * w_qkv[hc][c];  B3[d] = b_out[d] + w2s.BE
    const int c = t & 255, hf = t >> 8;
    const int h0 = hf * 256;
    float s0 = 0.f, s1 = 0.f;
    #pragma unroll 8
    for (int i = 0; i < 256; i += 2) {
        s0 += w2s[h0 + i]     * w_qkv[(size_t)(h0 + i) * 256 + c];
        s1 += w2s[h0 + i + 1] * w_qkv[(size_t)(h0 + i + 1) * 256 + c];
    }
    ps[t] = s0 + s1;
    if (hf == 0) red[c] = w2s[c] * BE[c] + w2s[256 + c] * BE[256 + c];
    __syncthreads();
    if (hf == 0) {
        const int g = c >> 3;
        const float inv_n = 1.f / (float)(CPG * LSEQ);
        float mu  = gsum[g] * inv_n;
        float var = gsumsq[g] * inv_n - mu * mu;
        float a = gn_w[c] * rsqrtf(var + EPS);
        W3B[(size_t)d * 256 + c] = f2bs((ps[c] + ps[256 + c]) * a);
    }
    for (int off = 128; off > 0; off >>= 1) {
        if (hf == 0 && c < off) red[c] += red[c + off];
        __syncthreads();
    }
    if (t == 0) B3[d] = b_out[d] + red[0];
}

// ============ final GEMM: out = W3B @ xT + b3 (glds staging + swizzle + setprio) ============
// grid 1024: m0 = (bid>>9)*128, chunk = bid&511. Wave owns 32 rows x 64 cols.
__global__ __launch_bounds__(256, 2) void k_final(const ushort_t* __restrict__ XT,
                                                  const ushort_t* __restrict__ W3B,
                                                  const float* __restrict__ B3,
                                                  float* __restrict__ out) {
    __shared__ __align__(16) ushort_t xs[64 * 256];
    const int tid  = threadIdx.x;
    const int lane = tid & 63;
    const int wv   = __builtin_amdgcn_readfirstlane(tid >> 6);
    const int ln   = lane & 15;
    const int q    = lane >> 4;
    const int m0   = (blockIdx.x >> 9) * 128;
    const int l0   = (blockIdx.x & 511) * 64;

    const int srow = lane >> 5;
    const int sg   = lane & 31;

    // stage 64 rows via global_load_lds w16, XOR-swizzled source granules
    #pragma unroll
    for (int kk = 0; kk < 8; kk++) {
        const int row = wv*16 + kk*2 + srow;
        glds16(XT + (size_t)(l0 + row) * 256 + ((sg ^ (row & 7)) << 3),
               &xs[(wv*16 + kk*2) * 256]);
    }

    sfrag8 Af[2][8];
    #pragma unroll
    for (int mt = 0; mt < 2; mt++) {
        const ushort_t* ap = W3B + (size_t)(m0 + wv*32 + mt*16 + ln) * 256 + q*8;
        #pragma unroll
        for (int k0 = 0; k0 < 8; k0++) Af[mt][k0] = *(const sfrag8*)(ap + k0*32);
    }
    float bias[2][4];
    #pragma unroll
    for (int mt = 0; mt < 2; mt++)
        #pragma unroll
        for (int r = 0; r < 4; r++)
            bias[mt][r] = B3[m0 + wv*32 + mt*16 + q*4 + r];

    asm volatile("s_waitcnt vmcnt(0)" ::: "memory");
    __builtin_amdgcn_s_barrier();

    f32x4 acc[2][4];
    #pragma unroll
    for (int mt = 0; mt < 2; mt++)
        #pragma unroll
        for (int nt = 0; nt < 4; nt++)
            #pragma unroll
            for (int e = 0; e < 4; e++) acc[mt][nt][e] = 0.f;

    __builtin_amdgcn_s_setprio(1);
    #pragma unroll
    for (int k0 = 0; k0 < 8; k0++) {
        const int gg0 = ((k0*4 + q) ^ (ln & 7)) << 3;
        sfrag8 b0 = *(const sfrag8*)&xs[(0*16 + ln) * 256 + gg0];
        sfrag8 b1 = *(const sfrag8*)&xs[(1*16 + ln) * 256 + gg0];
        sfrag8 b2 = *(const sfrag8*)&xs[(2*16 + ln) * 256 + gg0];
        sfrag8 b3 = *(const sfrag8*)&xs[(3*16 + ln) * 256 + gg0];
        #pragma unroll
        for (int mt = 0; mt < 2; mt++) {
            acc[mt][0] = __builtin_amdgcn_mfma_f32_16x16x32_bf16(Af[mt][k0], b0, acc[mt][0], 0, 0, 0);
            acc[mt][1] = __builtin_amdgcn_mfma_f32_16x16x32_bf16(Af[mt][k0], b1, acc[mt][1], 0, 0, 0);
            acc[mt][2] = __builtin_amdgcn_mfma_f32_16x16x32_bf16(Af[mt][k0], b2, acc[mt][2], 0, 0, 0);
            acc[mt][3] = __builtin_amdgcn_mfma_f32_16x16x32_bf16(Af[mt][k0], b3, acc[mt][3], 0, 0, 0);
        }
    }
    __builtin_amdgcn_s_setprio(0);

    #pragma unroll
    for (int mt = 0; mt < 2; mt++)
        #pragma unroll
        for (int nt = 0; nt < 4; nt++)
            #pragma unroll
            for (int r = 0; r < 4; r++) {
                int row = m0 + wv*32 + mt*16 + q*4 + r;
                int col = l0 + nt*16 + ln;
                out[(size_t)row * LSEQ + col] = acc[mt][nt][r] + bias[mt][r];
            }
}

// ============ launch ============
extern "C" void kernel_launch(void* const* d_in, const int* in_sizes, int n_in,
                              void* d_out, int out_size, void* d_ws, size_t ws_size,
                              hipStream_t stream) {
    const float* x     = (const float*)d_in[0];
    const float* gn_w  = (const float*)d_in[1];
    const float* gn_b  = (const float*)d_in[2];
    const float* w_qkv = (const float*)d_in[3];
    const float* b_qkv = (const float*)d_in[4];
    const float* w_out = (const float*)d_in[5];
    const float* b_out = (const float*)d_in[6];
    float* out = (float*)d_out;
    float* ws  = (float*)d_ws;

    float*    gsum   = ws + 0;        // 32
    float*    gsumsq = ws + 32;       // 32   [memset covers 64 floats]
    float*    S      = ws + 64;       // 32768 [zeroed by k_fold]
    float*    Z      = ws + 32832;    // 512   [zeroed by k_fold]
    float*    BE     = ws + 33856;    // 1536
    float*    BE2    = ws + 35392;    // 1024
    ushort_t* WEB    = (ushort_t*)(ws + 36416);    // 1024*256 bf16 (65536 f)
    ushort_t* W3B    = (ushort_t*)(ws + 233024);   // 256*256 bf16 (32768 f)
    float*    B3     = ws + 265792;   // 256
    ushort_t* XT     = (ushort_t*)(ws + 266048);   // 32768*256 bf16 (4194304 f)

    hipMemsetAsync(ws, 0, 64 * sizeof(float), stream);   // gsum, gsumsq only
    k_tr    <<<512,  256, 0, stream>>>(x, XT, gsum, gsumsq);
    k_fold  <<<1536, 256, 0, stream>>>(gn_w, gn_b, gsum, gsumsq, w_qkv, b_qkv,
                                       WEB, BE, BE2, S, Z);
    k_attn  <<<512,  256, 0, stream>>>(XT, WEB, BE2, S, Z);
    k_w23   <<<256,  512, 0, stream>>>(w_out, S, Z, w_qkv, BE, gn_w, gsum, gsumsq,
                                       b_out, W3B, B3);
    k_final <<<1024, 256, 0, stream>>>(XT, W3B, B3, out);
}